// Round 9
// baseline (23960.913 us; speedup 1.0000x reference)
//
#include <hip/hip_runtime.h>
#include <hip/hip_bf16.h>
#include <hip/hip_fp16.h>
#include <math.h>

#define Bdim 128
#define Tdim 96
#define Fdim 64
#define Sdim 16
#define Rdim 6
#define KACT 4
#define Hdim 128
#define DK 64
#define DV 128
#define HC 4
#define CK 32
#define CV 32

__device__ __forceinline__ float sigmoidf_(float x) { return 1.0f / (1.0f + expf(-x)); }

__device__ __forceinline__ float2 h2f(float w) {
    union { float f; __half2 h; } u; u.f = w;
    return __half22float2(u.h);
}

// 16 MACs: 4 K-values (hq) x 4 cols; weights given as two float4 (16 packed halves)
__device__ __forceinline__ void fma16v(float4& acc, const float4 wa, const float4 wb, const float4 hq) {
    float2 c;
    c = h2f(wa.x); acc.x += hq.x * c.x; acc.y += hq.x * c.y;
    c = h2f(wa.y); acc.z += hq.x * c.x; acc.w += hq.x * c.y;
    c = h2f(wa.z); acc.x += hq.y * c.x; acc.y += hq.y * c.y;
    c = h2f(wa.w); acc.z += hq.y * c.x; acc.w += hq.y * c.y;
    c = h2f(wb.x); acc.x += hq.z * c.x; acc.y += hq.z * c.y;
    c = h2f(wb.y); acc.z += hq.z * c.x; acc.w += hq.z * c.y;
    c = h2f(wb.z); acc.x += hq.w * c.x; acc.y += hq.w * c.y;
    c = h2f(wb.w); acc.z += hq.w * c.x; acc.w += hq.w * c.y;
}

// ---------------- Kernel 1: precompute gamma_h, k, v for all (b,t) ----------------
__global__ __launch_bounds__(128) void k_pre(
    const float* __restrict__ x, const float* __restrict__ mask,
    const float* __restrict__ delta, const float* __restrict__ xlast,
    const float* __restrict__ xmean,
    const float* __restrict__ Wgx, const float* __restrict__ bgx,
    const float* __restrict__ Wgh, const float* __restrict__ bgh,
    const float* __restrict__ Wk, const float* __restrict__ bk,
    const float* __restrict__ Wv, const float* __restrict__ bv,
    float* __restrict__ ghO, float* __restrict__ kO, float* __restrict__ vO)
{
    const int bt = blockIdx.x;
    const int b = bt / Tdim, t = bt % Tdim;
    const int tid = threadIdx.x;
    __shared__ float d_s[Fdim], xh_s[Fdim];
    const int base = (b * Tdim + t) * Fdim;

    if (tid < Fdim) d_s[tid] = delta[base + tid];
    __syncthreads();

    if (tid < Fdim) {
        float z = bgx[tid];
        #pragma unroll 8
        for (int i = 0; i < Fdim; ++i) z += d_s[i] * Wgx[i * Fdim + tid];
        float gx = expf(-fmaxf(z, 0.0f));
        float m = mask[base + tid], xv = x[base + tid];
        float xl = xlast[base + tid], xm = xmean[b * Fdim + tid];
        xh_s[tid] = m * xv + (1.0f - m) * (gx * xl + (1.0f - gx) * xm);
    }
    {
        float z = bgh[tid];
        #pragma unroll 8
        for (int i = 0; i < Fdim; ++i) z += d_s[i] * Wgh[i * Hdim + tid];
        ghO[(size_t)(b * Tdim + t) * Hdim + tid] = expf(-fmaxf(z, 0.0f));
    }
    __syncthreads();

    if (tid < DK) {
        float z = bk[tid];
        #pragma unroll 8
        for (int j = 0; j < Fdim; ++j) z += xh_s[j] * Wk[j * DK + tid];
        kO[(size_t)(b * Tdim + t) * DK + tid] = z;
    }
    {
        float z = bv[tid];
        #pragma unroll 8
        for (int j = 0; j < Fdim; ++j) z += xh_s[j] * Wv[j * DV + tid];
        vO[(size_t)(b * Tdim + t) * DV + tid] = z;
    }
}

// ---------------- Kernel 1b: BX[r,c] = bv @ Wx_rnn[r];  WB[r,h] = Wq_in[r,h,:]·bk ----------------
__global__ __launch_bounds__(256) void k_bx(
    const float* __restrict__ bv, const float* __restrict__ Wx_rnn,
    const float* __restrict__ bk, const float* __restrict__ Wq_in,
    float* __restrict__ BX, float* __restrict__ WB)
{
    int c = blockIdx.x * 256 + threadIdx.x;
    if (c < Rdim * 512) {
        int r = c >> 9, cc = c & 511;
        float acc = 0.0f;
        #pragma unroll 4
        for (int d = 0; d < DV; ++d)
            acc += bv[d] * Wx_rnn[((size_t)r * DV + d) * 512 + cc];
        BX[c] = acc;
    } else if (c < Rdim * 512 + Rdim * Hdim) {
        int i = c - Rdim * 512;
        int r = i >> 7, h = i & 127;
        float acc = 0.0f;
        #pragma unroll 8
        for (int d = 0; d < DK; ++d)
            acc += Wq_in[((size_t)r * Hdim + h) * DK + d] * bk[d];
        WB[i] = acc;
    }
}

// ---------------- Kernel 1c: VX gate-major: VX[bt][r][j][g] = v[bt,:]·Wx[r][:, g*128+j] ----------------
#define VX_BT 32
__global__ __launch_bounds__(256) void k_vx(
    const float* __restrict__ vG, const float* __restrict__ Wx_rnn,
    float* __restrict__ VX32, __half* __restrict__ VX16, const int m16)
{
    const int bt0 = blockIdx.x * VX_BT;
    const int r = blockIdx.y;
    const int g = blockIdx.z;                 // gate 0..3
    const int j = threadIdx.x & 127;
    const int c = g * 128 + j;
    const int half_ = threadIdx.x >> 7;
    __shared__ float vv_s[VX_BT][DV];

    for (int i = threadIdx.x; i < VX_BT * DV; i += 256)
        vv_s[i >> 7][i & 127] = vG[(size_t)(bt0 + (i >> 7)) * DV + (i & 127)];
    __syncthreads();

    float acc[16];
    #pragma unroll
    for (int i = 0; i < 16; ++i) acc[i] = 0.0f;

    const float* wp = Wx_rnn + ((size_t)r * DV) * 512 + c;
    const int btb = half_ * 16;
    #pragma unroll 4
    for (int d = 0; d < DV; ++d) {
        float w = wp[(size_t)d * 512];
        #pragma unroll
        for (int i = 0; i < 16; ++i) acc[i] += vv_s[btb + i][d] * w;
    }
    #pragma unroll
    for (int i = 0; i < 16; ++i) {
        size_t idx = (((size_t)(bt0 + btb + i) * Rdim + r) * 128 + j) * 4 + g;
        if (m16) VX16[idx] = __float2half(acc[i]);
        else     VX32[idx] = acc[i];
    }
}

// ---------------- Kernel 1d: WK[bt,r,h] = Wq_in[r,h,:] · k[bt,:] ----------------
__global__ __launch_bounds__(256) void k_wk(
    const float* __restrict__ kG, const float* __restrict__ Wq_in,
    float* __restrict__ WK)
{
    const int bt0 = blockIdx.x * 32;
    const int r = blockIdx.y;
    __shared__ float ks[32][66];
    for (int e = threadIdx.x; e < 32 * 64; e += 256)
        ks[e >> 6][e & 63] = kG[(size_t)(bt0 + (e >> 6)) * DK + (e & 63)];
    __syncthreads();

    const int btl = threadIdx.x >> 3, hg = threadIdx.x & 7;
    const float* wq = Wq_in + (size_t)r * Hdim * DK;
    #pragma unroll 4
    for (int i = 0; i < 16; ++i) {
        int h = hg + i * 8;
        const float4* wr = (const float4*)(wq + (size_t)h * DK);
        float acc = 0.0f;
        #pragma unroll
        for (int d4 = 0; d4 < 16; ++d4) {
            float4 w = wr[d4];
            acc += w.x * ks[btl][d4 * 4] + w.y * ks[btl][d4 * 4 + 1]
                 + w.z * ks[btl][d4 * 4 + 2] + w.w * ks[btl][d4 * 4 + 3];
        }
        WK[((size_t)(bt0 + btl) * Rdim + r) * Hdim + h] = acc;
    }
}

// ---------------- Kernel 1e: fp16-pack hot weights ----------------
// Wh_p GATE-MAJOR: [r][d4<32][j<128][16], e<16: d=4*d4+(e>>2), gate g=e&3 -> Wh[r][d][g*128+j]
// Wc_p [r][d4<32][e4<96][16]: d=4*d4+(e>>2), col=4*e4+(e&3) over [q|k|v] 384 cols
// Wo_p [r][d4<32][c4<32][16]: d=4*d4+(e>>2), col=4*c4+(e&3)
#define NH_P (Rdim * 32 * 128 * 16)
#define NC_P (Rdim * 32 * 96 * 16)
#define NO_P (Rdim * 32 * 32 * 16)
__global__ __launch_bounds__(256) void k_pack(
    const float* __restrict__ Wh_rnn,
    const float* __restrict__ Wq_c, const float* __restrict__ Wk_c,
    const float* __restrict__ Wv_c, const float* __restrict__ Wout_c,
    __half* __restrict__ Wh_p, __half* __restrict__ Wc_p, __half* __restrict__ Wo_p)
{
    int i = blockIdx.x * 256 + threadIdx.x;
    if (i < NH_P) {
        int e = i & 15, t1 = i >> 4;
        int j = t1 & 127, t2 = t1 >> 7;
        int d4 = t2 & 31, r = t2 >> 5;
        int d = 4 * d4 + (e >> 2), g = e & 3;
        Wh_p[i] = __float2half(Wh_rnn[((size_t)r * Hdim + d) * 512 + g * 128 + j]);
    } else if (i < NH_P + NC_P) {
        int ii = i - NH_P;
        int e = ii & 15, t1 = ii >> 4;
        int e4 = t1 % 96, t2 = t1 / 96;
        int d4 = t2 & 31, r = t2 >> 5;
        int d = 4 * d4 + (e >> 2), col = 4 * e4 + (e & 3);
        int mId = col >> 7, colm = col & 127;
        const float* src = (mId == 0 ? Wq_c : (mId == 1 ? Wk_c : Wv_c));
        Wc_p[ii] = __float2half(src[((size_t)r * Hdim + d) * Hdim + colm]);
    } else if (i < NH_P + NC_P + NO_P) {
        int ii = i - NH_P - NC_P;
        int e = ii & 15, t1 = ii >> 4;
        int c4 = t1 & 31, t2 = t1 >> 5;
        int d4 = t2 & 31, r = t2 >> 5;
        int d = 4 * d4 + (e >> 2), col = 4 * c4 + (e & 3);
        Wo_p[ii] = __float2half(Wout_c[((size_t)r * Hdim + d) * Hdim + col]);
    }
}

// round-5 proven register style: function-scope arrays + loop-carried dbuf
#define LOADC(BUF, PBASE, CIDX, DSTRIDE)                                          \
    {                                                                             \
        const __half* _b = (PBASE) + (size_t)(CIDX) * 4 * (DSTRIDE);              \
        _Pragma("unroll")                                                         \
        for (int _q = 0; _q < 4; ++_q) {                                          \
            const float4* _p = (const float4*)(_b + (size_t)_q * (DSTRIDE));      \
            BUF[2 * _q] = _p[0]; BUF[2 * _q + 1] = _p[1];                         \
        }                                                                         \
    }
#define FMAC(BUF, ACC, ROWPTR, CIDX)                                              \
    {                                                                             \
        _Pragma("unroll")                                                         \
        for (int _q = 0; _q < 4; ++_q) {                                          \
            float4 _hq = *(const float4*)((ROWPTR) + ((CIDX) * 4 + _q) * 4);      \
            fma16v(ACC, BUF[2 * _q], BUF[2 * _q + 1], _hq);                       \
        }                                                                         \
    }

// ---------------- Kernel 2: sequential scan, 4 barriers/step ----------------
__global__ __launch_bounds__(768) void k_seq(
    const float* __restrict__ statics,
    const float* __restrict__ h0, const float* __restrict__ c0,
    const __half* __restrict__ Wh_p, const __half* __restrict__ Wc_p,
    const __half* __restrict__ Wo_p,
    const float* __restrict__ b_rnn,
    const float* __restrict__ W1, const float* __restrict__ b1,
    const float* __restrict__ W2, const float* __restrict__ b2,
    const float* __restrict__ ghG, const float* __restrict__ WK,
    const float* __restrict__ WB,
    const float* __restrict__ VX32, const __half* __restrict__ VX16, const int m16,
    const float* __restrict__ BX,
    float* __restrict__ out)
{
    const int b = blockIdx.x;
    const int tid = threadIdx.x;
    const int wave = tid >> 6, lane = tid & 63;
    const int r_ = tid >> 7, j_ = tid & 127;   // note: r_ == wave >> 1

    __shared__ float hs[Rdim][Hdim], cs[Rdim][Hdim], hn[Rdim][Hdim], cn[Rdim][Hdim];
    __shared__ float qc[Rdim][Hdim], kc[Rdim][Hdim], vc[Rdim][Hdim], ctx[Rdim][Hdim];
    __shared__ float BX_s[Rdim][512], brnn_s[Rdim][512];
    __shared__ float WB_s[Rdim][Hdim];
    __shared__ float s0s[8];

    ((float4*)&BX_s[0][0])[tid]   = ((const float4*)BX)[tid];
    ((float4*)&brnn_s[0][0])[tid] = ((const float4*)b_rnn)[tid];
    (&WB_s[0][0])[tid] = WB[tid];

    // per-step data prefetch for t=0
    int bt = b * Tdim;
    float ghr = ghG[(size_t)bt * Hdim + j_];
    float4 vx4;
    if (m16) {
        const __half2* vp = (const __half2*)(VX16 + (((size_t)bt * Rdim + r_) * 128 + j_) * 4);
        float2 a = __half22float2(vp[0]), bb = __half22float2(vp[1]);
        vx4 = make_float4(a.x, a.y, bb.x, bb.y);
    } else {
        vx4 = *(const float4*)(VX32 + (((size_t)bt * Rdim + r_) * 128 + j_) * 4);
    }
    float wk0 = WK[((size_t)bt * Rdim + r_) * Hdim + lane];
    float wk1 = WK[((size_t)bt * Rdim + r_) * Hdim + lane + 64];

    hs[r_][j_] = h0[(size_t)b * 768 + tid] * ghr;
    cs[r_][j_] = c0[(size_t)b * 768 + tid];
    __syncthreads();

    const __half* whp = Wh_p + ((size_t)r_ * 32 * 128 + j_) * 16;   // d4-stride 2048 halves
    float4 wbA[8], wbB[8];

    for (int t = 0; t < Tdim; ++t) {
        bt = b * Tdim + t;
        const bool lastt = (t == Tdim - 1);

        // ==== P1: in-wave scores + Wh matvec (dbuf) + fused LSTM ====
        LOADC(wbA, whp, 0, 2048);
        float p0v, p1v;
        {
            // each wave-pair redundantly computes the score of its row r_
            float hv0 = hs[r_][lane], hv1 = hs[r_][lane + 64];
            float a0 = hv0 * wk0 + hv1 * wk1;
            float a1 = hv0 * WB_s[r_][lane] + hv1 * WB_s[r_][lane + 64];
            #pragma unroll
            for (int off = 32; off > 0; off >>= 1) {
                a0 += __shfl_xor(a0, off);
                a1 += __shfl_xor(a1, off);
            }
            float sv0 = a0 * 0.125f, sv1 = a1 * 0.125f;
            float mm = fmaxf(sv0, sv1);
            float e0 = expf(sv0 - mm), e1 = expf(sv1 - mm);
            float inv = 1.0f / (e0 + e1);
            p0v = e0 * inv; p1v = e1 * inv;
            if ((wave & 1) == 0 && lane == 0) s0s[r_] = sv0;
        }
        {
            float4 acc = make_float4(0.f, 0.f, 0.f, 0.f);
            const float* hrow = &hs[r_][0];
            #pragma unroll
            for (int c = 0; c < 8; c += 2) {
                if (c + 1 < 8) LOADC(wbB, whp, c + 1, 2048);
                FMAC(wbA, acc, hrow, c);
                if (c + 2 < 8) LOADC(wbA, whp, c + 2, 2048);
                FMAC(wbB, acc, hrow, c + 1);
            }
            float ig = acc.x + p0v * vx4.x + p1v * BX_s[r_][j_]       + brnn_s[r_][j_];
            float fg = acc.y + p0v * vx4.y + p1v * BX_s[r_][128 + j_] + brnn_s[r_][128 + j_];
            float gg = acc.z + p0v * vx4.z + p1v * BX_s[r_][256 + j_] + brnn_s[r_][256 + j_];
            float og = acc.w + p0v * vx4.w + p1v * BX_s[r_][384 + j_] + brnn_s[r_][384 + j_];
            float cnew = sigmoidf_(fg) * cs[r_][j_] + sigmoidf_(ig) * tanhf(gg);
            float hnew = sigmoidf_(og) * tanhf(cnew);
            cn[r_][j_] = cnew;
            hn[r_][j_] = hnew;
        }
        __syncthreads();

        // ==== P3: t+1 per-step prefetch (all) + Wc qkv matvec (576 thr, dbuf) ====
        if (!lastt) {
            const int bt1 = bt + 1;
            ghr = ghG[(size_t)bt1 * Hdim + j_];
            if (m16) {
                const __half2* vp = (const __half2*)(VX16 + (((size_t)bt1 * Rdim + r_) * 128 + j_) * 4);
                float2 a = __half22float2(vp[0]), bb = __half22float2(vp[1]);
                vx4 = make_float4(a.x, a.y, bb.x, bb.y);
            } else {
                vx4 = *(const float4*)(VX32 + (((size_t)bt1 * Rdim + r_) * 128 + j_) * 4);
            }
            wk0 = WK[((size_t)bt1 * Rdim + r_) * Hdim + lane];
            wk1 = WK[((size_t)bt1 * Rdim + r_) * Hdim + lane + 64];
        } else {
            ghr = 1.0f;
        }
        if (tid < 576) {
            const int rG = tid / 96, e4 = tid % 96;
            const __half* wcp = Wc_p + ((size_t)rG * 32 * 96 + e4) * 16;   // d4-stride 1536
            float4 acc = make_float4(0.f, 0.f, 0.f, 0.f);
            const float* hrow = &hn[rG][0];
            LOADC(wbA, wcp, 0, 1536);
            #pragma unroll
            for (int c = 0; c < 8; c += 2) {
                if (c + 1 < 8) LOADC(wbB, wcp, c + 1, 1536);
                FMAC(wbA, acc, hrow, c);
                if (c + 2 < 8) LOADC(wbA, wcp, c + 2, 1536);
                FMAC(wbB, acc, hrow, c + 1);
            }
            int col = e4 * 4, mId = col >> 7, colm = col & 127;
            float* dst = (mId == 0 ? &qc[rG][colm] : (mId == 1 ? &kc[rG][colm] : &vc[rG][colm]));
            *(float4*)dst = acc;
        }
        __syncthreads();

        // ==== P4: attention (tid 512-607, regs) + Wo chunk0 prefetch (tid<192) ====
        if (tid < 192) {
            const int rK = tid / 32, c4 = tid % 32;
            const __half* wop = Wo_p + ((size_t)rK * 32 * 32 + c4) * 16;   // d4-stride 512
            LOADC(wbA, wop, 0, 512);
        } else if (tid >= 512 && tid < 608) {
            const int tl = tid - 512;
            const int rr = tl >> 4, h = (tl >> 2) & 3, q = tl & 3;
            float4 Q[8];
            #pragma unroll
            for (int i = 0; i < 8; ++i) Q[i] = *(const float4*)&qc[rr][h * 32 + 4 * i];
            float sc[Rdim];
            #pragma unroll
            for (int ss = 0; ss < Rdim; ++ss) {
                float acc = 0.0f;
                #pragma unroll
                for (int i = 0; i < 8; ++i) {
                    float4 kq = *(const float4*)&kc[ss][h * 32 + 4 * i];
                    acc += Q[i].x * kq.x + Q[i].y * kq.y + Q[i].z * kq.z + Q[i].w * kq.w;
                }
                sc[ss] = acc * 0.17677669529663687f;
            }
            float m = sc[0];
            #pragma unroll
            for (int ss = 1; ss < Rdim; ++ss) m = fmaxf(m, sc[ss]);
            float e[Rdim], sum = 0.0f;
            #pragma unroll
            for (int ss = 0; ss < Rdim; ++ss) { e[ss] = expf(sc[ss] - m); sum += e[ss]; }
            int rank = 0;
            #pragma unroll
            for (int jj = 0; jj < Rdim; ++jj)
                rank += (s0s[jj] > s0s[rr] || (s0s[jj] == s0s[rr] && jj < rr)) ? 1 : 0;
            float w = ((rank < KACT) ? 1.0f : 0.0f) / sum;
            float4 a0 = make_float4(0.f, 0.f, 0.f, 0.f), a1 = a0;
            #pragma unroll
            for (int ss = 0; ss < Rdim; ++ss) {
                float cl = e[ss] * w;
                float4 v0 = *(const float4*)&vc[ss][h * 32 + q * 8];
                float4 v1 = *(const float4*)&vc[ss][h * 32 + q * 8 + 4];
                a0.x += cl * v0.x; a0.y += cl * v0.y; a0.z += cl * v0.z; a0.w += cl * v0.w;
                a1.x += cl * v1.x; a1.y += cl * v1.y; a1.z += cl * v1.z; a1.w += cl * v1.w;
            }
            *(float4*)&ctx[rr][h * 32 + q * 8] = a0;
            *(float4*)&ctx[rr][h * 32 + q * 8 + 4] = a1;
        }
        __syncthreads();

        // ==== P5: Wout (tid<192, dbuf) + state update + decay(t+1) ====
        if (tid < 192) {
            const int rK = tid / 32, c4 = tid % 32;
            int rankK = 0;
            #pragma unroll
            for (int jj = 0; jj < Rdim; ++jj)
                rankK += (s0s[jj] > s0s[rK] || (s0s[jj] == s0s[rK] && jj < rK)) ? 1 : 0;
            if (rankK < KACT) {
                const __half* wop = Wo_p + ((size_t)rK * 32 * 32 + c4) * 16;
                float4 acc = make_float4(0.f, 0.f, 0.f, 0.f);
                const float* crow = &ctx[rK][0];
                #pragma unroll
                for (int c = 0; c < 8; c += 2) {
                    if (c + 1 < 8) LOADC(wbB, wop, c + 1, 512);
                    FMAC(wbA, acc, crow, c);
                    if (c + 2 < 8) LOADC(wbA, wop, c + 2, 512);
                    FMAC(wbB, acc, crow, c + 1);
                }
                float4 hq = *(const float4*)&hn[rK][c4 * 4];
                float4 g4 = make_float4(1.f, 1.f, 1.f, 1.f);
                if (!lastt) g4 = *(const float4*)&ghG[(size_t)(bt + 1) * Hdim + c4 * 4];
                float4 o;
                o.x = (acc.x + hq.x) * g4.x;
                o.y = (acc.y + hq.y) * g4.y;
                o.z = (acc.z + hq.z) * g4.z;
                o.w = (acc.w + hq.w) * g4.w;
                *(float4*)&hs[rK][c4 * 4] = o;
            }
        }
        {
            int rank = 0;
            #pragma unroll
            for (int jj = 0; jj < Rdim; ++jj)
                rank += (s0s[jj] > s0s[r_] || (s0s[jj] == s0s[r_] && jj < r_)) ? 1 : 0;
            if (rank < KACT) cs[r_][j_] = cn[r_][j_];
            else             hs[r_][j_] *= ghr;     // inactive: keep decayed h_old
        }
        __syncthreads();
    }

    // Head
    if (tid < 64) {
        float a = b1[tid];
        const float* hsf = &hs[0][0];
        #pragma unroll 4
        for (int i = 0; i < Rdim * Hdim; ++i) a += hsf[i] * W1[i * 64 + tid];
        #pragma unroll
        for (int i = 0; i < Sdim; ++i) a += statics[b * Sdim + i] * W1[(Rdim * Hdim + i) * 64 + tid];
        float pv = a * W2[tid];
        #pragma unroll
        for (int off = 32; off > 0; off >>= 1) pv += __shfl_xor(pv, off);
        if (tid == 0) out[b] = pv + b2[0];
    }
}

extern "C" void kernel_launch(void* const* d_in, const int* in_sizes, int n_in,
                              void* d_out, int out_size, void* d_ws, size_t ws_size,
                              hipStream_t stream) {
    const float* x       = (const float*)d_in[0];
    const float* statics = (const float*)d_in[1];
    const float* mask    = (const float*)d_in[2];
    const float* delta   = (const float*)d_in[3];
    const float* xlast   = (const float*)d_in[4];
    const float* xmean   = (const float*)d_in[5];
    const float* h0      = (const float*)d_in[6];
    const float* c0      = (const float*)d_in[7];
    const float* Wgx     = (const float*)d_in[8];
    const float* bgx     = (const float*)d_in[9];
    const float* Wgh     = (const float*)d_in[10];
    const float* bgh     = (const float*)d_in[11];
    const float* Wk_in   = (const float*)d_in[12];
    const float* bk_in   = (const float*)d_in[13];
    const float* Wv_in   = (const float*)d_in[14];
    const float* bv_in   = (const float*)d_in[15];
    const float* Wq_in   = (const float*)d_in[16];
    const float* Wx_rnn  = (const float*)d_in[17];
    const float* Wh_rnn  = (const float*)d_in[18];
    const float* b_rnn   = (const float*)d_in[19];
    const float* Wq_c    = (const float*)d_in[20];
    const float* Wk_c    = (const float*)d_in[21];
    const float* Wv_c    = (const float*)d_in[22];
    const float* Wout_c  = (const float*)d_in[23];
    const float* W1      = (const float*)d_in[24];
    const float* b1      = (const float*)d_in[25];
    const float* W2      = (const float*)d_in[26];
    const float* b2      = (const float*)d_in[27];

    const size_t nGh  = (size_t)Bdim * Tdim * Hdim;
    const size_t nK   = (size_t)Bdim * Tdim * DK;
    const size_t nV   = (size_t)Bdim * Tdim * DV;
    const size_t nBX  = (size_t)Rdim * 512;
    const size_t nWB  = (size_t)Rdim * Hdim;
    const size_t nWK  = (size_t)Bdim * Tdim * Rdim * Hdim;
    const size_t nPck = (size_t)(NH_P + NC_P + NO_P) / 2;
    const size_t nVX  = (size_t)Bdim * Tdim * Rdim * 512;

    float*  ws   = (float*)d_ws;
    float*  ghG  = ws;
    float*  kG   = ghG + nGh;
    float*  vG   = kG + nK;
    float*  BX   = vG + nV;
    float*  WB   = BX + nBX;
    float*  WK   = WB + nWB;
    __half* Wh_p = (__half*)(WK + nWK);
    __half* Wc_p = Wh_p + NH_P;
    __half* Wo_p = Wc_p + NC_P;
    float*  VXf  = WK + nWK + nPck;
    __half* VXh  = (__half*)VXf;

    const size_t base = nGh + nK + nV + nBX + nWB + nWK + nPck;
    const int m16 = (ws_size >= (base + nVX) * sizeof(float)) ? 0 : 1;

    k_pre<<<dim3(Bdim * Tdim), dim3(128), 0, stream>>>(
        x, mask, delta, xlast, xmean, Wgx, bgx, Wgh, bgh,
        Wk_in, bk_in, Wv_in, bv_in, ghG, kG, vG);

    k_bx<<<dim3((Rdim * 512 + Rdim * Hdim + 255) / 256), dim3(256), 0, stream>>>(
        bv_in, Wx_rnn, bk_in, Wq_in, BX, WB);

    k_wk<<<dim3(Bdim * Tdim / 32, Rdim), dim3(256), 0, stream>>>(kG, Wq_in, WK);

    k_pack<<<dim3((NH_P + NC_P + NO_P + 255) / 256), dim3(256), 0, stream>>>(
        Wh_rnn, Wq_c, Wk_c, Wv_c, Wout_c, Wh_p, Wc_p, Wo_p);

    k_vx<<<dim3(Bdim * Tdim / VX_BT, Rdim, 4), dim3(256), 0, stream>>>(
        vG, Wx_rnn, VXf, VXh, m16);

    k_seq<<<dim3(Bdim), dim3(768), 0, stream>>>(
        statics, h0, c0, Wh_p, Wc_p, Wo_p, b_rnn,
        W1, b1, W2, b2, ghG, WK, WB, VXf, VXh, m16, BX, (float*)d_out);
}

// Round 10
// 21513.861 us; speedup vs baseline: 1.1137x; 1.1137x over previous
//
#include <hip/hip_runtime.h>
#include <hip/hip_bf16.h>
#include <hip/hip_fp16.h>
#include <math.h>

#define Bdim 128
#define Tdim 96
#define Fdim 64
#define Sdim 16
#define Rdim 6
#define KACT 4
#define Hdim 128
#define DK 64
#define DV 128
#define HC 4
#define CK 32
#define CV 32

__device__ __forceinline__ float sigmoidf_(float x) { return 1.0f / (1.0f + expf(-x)); }

__device__ __forceinline__ float2 h2f(float w) {
    union { float f; __half2 h; } u; u.f = w;
    return __half22float2(u.h);
}

// 16 MACs: 4 K-values (hq) x 4 cols; weights given as two float4 (16 packed halves)
__device__ __forceinline__ void fma16v(float4& acc, const float4 wa, const float4 wb, const float4 hq) {
    float2 c;
    c = h2f(wa.x); acc.x += hq.x * c.x; acc.y += hq.x * c.y;
    c = h2f(wa.y); acc.z += hq.x * c.x; acc.w += hq.x * c.y;
    c = h2f(wa.z); acc.x += hq.y * c.x; acc.y += hq.y * c.y;
    c = h2f(wa.w); acc.z += hq.y * c.x; acc.w += hq.y * c.y;
    c = h2f(wb.x); acc.x += hq.z * c.x; acc.y += hq.z * c.y;
    c = h2f(wb.y); acc.z += hq.z * c.x; acc.w += hq.z * c.y;
    c = h2f(wb.z); acc.x += hq.w * c.x; acc.y += hq.w * c.y;
    c = h2f(wb.w); acc.z += hq.w * c.x; acc.w += hq.w * c.y;
}

// ---------------- Kernel 1: precompute gamma_h, k, v for all (b,t) ----------------
__global__ __launch_bounds__(128) void k_pre(
    const float* __restrict__ x, const float* __restrict__ mask,
    const float* __restrict__ delta, const float* __restrict__ xlast,
    const float* __restrict__ xmean,
    const float* __restrict__ Wgx, const float* __restrict__ bgx,
    const float* __restrict__ Wgh, const float* __restrict__ bgh,
    const float* __restrict__ Wk, const float* __restrict__ bk,
    const float* __restrict__ Wv, const float* __restrict__ bv,
    float* __restrict__ ghO, float* __restrict__ kO, float* __restrict__ vO)
{
    const int bt = blockIdx.x;
    const int b = bt / Tdim, t = bt % Tdim;
    const int tid = threadIdx.x;
    __shared__ float d_s[Fdim], xh_s[Fdim];
    const int base = (b * Tdim + t) * Fdim;

    if (tid < Fdim) d_s[tid] = delta[base + tid];
    __syncthreads();

    if (tid < Fdim) {
        float z = bgx[tid];
        #pragma unroll 8
        for (int i = 0; i < Fdim; ++i) z += d_s[i] * Wgx[i * Fdim + tid];
        float gx = expf(-fmaxf(z, 0.0f));
        float m = mask[base + tid], xv = x[base + tid];
        float xl = xlast[base + tid], xm = xmean[b * Fdim + tid];
        xh_s[tid] = m * xv + (1.0f - m) * (gx * xl + (1.0f - gx) * xm);
    }
    {
        float z = bgh[tid];
        #pragma unroll 8
        for (int i = 0; i < Fdim; ++i) z += d_s[i] * Wgh[i * Hdim + tid];
        ghO[(size_t)(b * Tdim + t) * Hdim + tid] = expf(-fmaxf(z, 0.0f));
    }
    __syncthreads();

    if (tid < DK) {
        float z = bk[tid];
        #pragma unroll 8
        for (int j = 0; j < Fdim; ++j) z += xh_s[j] * Wk[j * DK + tid];
        kO[(size_t)(b * Tdim + t) * DK + tid] = z;
    }
    {
        float z = bv[tid];
        #pragma unroll 8
        for (int j = 0; j < Fdim; ++j) z += xh_s[j] * Wv[j * DV + tid];
        vO[(size_t)(b * Tdim + t) * DV + tid] = z;
    }
}

// ---------------- Kernel 1b: BX[r,c] = bv @ Wx_rnn[r];  WB[r,h] = Wq_in[r,h,:]·bk ----------------
__global__ __launch_bounds__(256) void k_bx(
    const float* __restrict__ bv, const float* __restrict__ Wx_rnn,
    const float* __restrict__ bk, const float* __restrict__ Wq_in,
    float* __restrict__ BX, float* __restrict__ WB)
{
    int c = blockIdx.x * 256 + threadIdx.x;
    if (c < Rdim * 512) {
        int r = c >> 9, cc = c & 511;
        float acc = 0.0f;
        #pragma unroll 4
        for (int d = 0; d < DV; ++d)
            acc += bv[d] * Wx_rnn[((size_t)r * DV + d) * 512 + cc];
        BX[c] = acc;
    } else if (c < Rdim * 512 + Rdim * Hdim) {
        int i = c - Rdim * 512;
        int r = i >> 7, h = i & 127;
        float acc = 0.0f;
        #pragma unroll 8
        for (int d = 0; d < DK; ++d)
            acc += Wq_in[((size_t)r * Hdim + h) * DK + d] * bk[d];
        WB[i] = acc;
    }
}

// ---------------- Kernel 1c: VX gate-major: VX[bt][r][j][g] = v[bt,:]·Wx[r][:, g*128+j] ----------------
#define VX_BT 32
__global__ __launch_bounds__(256) void k_vx(
    const float* __restrict__ vG, const float* __restrict__ Wx_rnn,
    float* __restrict__ VX32, __half* __restrict__ VX16, const int m16)
{
    const int bt0 = blockIdx.x * VX_BT;
    const int r = blockIdx.y;
    const int g = blockIdx.z;                 // gate 0..3
    const int j = threadIdx.x & 127;
    const int c = g * 128 + j;
    const int half_ = threadIdx.x >> 7;
    __shared__ float vv_s[VX_BT][DV];

    for (int i = threadIdx.x; i < VX_BT * DV; i += 256)
        vv_s[i >> 7][i & 127] = vG[(size_t)(bt0 + (i >> 7)) * DV + (i & 127)];
    __syncthreads();

    float acc[16];
    #pragma unroll
    for (int i = 0; i < 16; ++i) acc[i] = 0.0f;

    const float* wp = Wx_rnn + ((size_t)r * DV) * 512 + c;
    const int btb = half_ * 16;
    #pragma unroll 4
    for (int d = 0; d < DV; ++d) {
        float w = wp[(size_t)d * 512];
        #pragma unroll
        for (int i = 0; i < 16; ++i) acc[i] += vv_s[btb + i][d] * w;
    }
    #pragma unroll
    for (int i = 0; i < 16; ++i) {
        size_t idx = (((size_t)(bt0 + btb + i) * Rdim + r) * 128 + j) * 4 + g;
        if (m16) VX16[idx] = __float2half(acc[i]);
        else     VX32[idx] = acc[i];
    }
}

// ---------------- Kernel 1d: WK[bt,r,h] = Wq_in[r,h,:] · k[bt,:] ----------------
__global__ __launch_bounds__(256) void k_wk(
    const float* __restrict__ kG, const float* __restrict__ Wq_in,
    float* __restrict__ WK)
{
    const int bt0 = blockIdx.x * 32;
    const int r = blockIdx.y;
    __shared__ float ks[32][66];
    for (int e = threadIdx.x; e < 32 * 64; e += 256)
        ks[e >> 6][e & 63] = kG[(size_t)(bt0 + (e >> 6)) * DK + (e & 63)];
    __syncthreads();

    const int btl = threadIdx.x >> 3, hg = threadIdx.x & 7;
    const float* wq = Wq_in + (size_t)r * Hdim * DK;
    #pragma unroll 4
    for (int i = 0; i < 16; ++i) {
        int h = hg + i * 8;
        const float4* wr = (const float4*)(wq + (size_t)h * DK);
        float acc = 0.0f;
        #pragma unroll
        for (int d4 = 0; d4 < 16; ++d4) {
            float4 w = wr[d4];
            acc += w.x * ks[btl][d4 * 4] + w.y * ks[btl][d4 * 4 + 1]
                 + w.z * ks[btl][d4 * 4 + 2] + w.w * ks[btl][d4 * 4 + 3];
        }
        WK[((size_t)(bt0 + btl) * Rdim + r) * Hdim + h] = acc;
    }
}

// ---------------- Kernel 1e: fp16-pack hot weights ----------------
// Wh_p GATE-MAJOR: [r][d4<32][j<128][16], e<16: d=4*d4+(e>>2), gate g=e&3 -> Wh[r][d][g*128+j]
// Wc_p [r][d4<32][e4<96][16]: d=4*d4+(e>>2), col=4*e4+(e&3) over [q|k|v] 384 cols
// Wo_p [r][d4<32][c4<32][16]: d=4*d4+(e>>2), col=4*c4+(e&3)
#define NH_P (Rdim * 32 * 128 * 16)
#define NC_P (Rdim * 32 * 96 * 16)
#define NO_P (Rdim * 32 * 32 * 16)
__global__ __launch_bounds__(256) void k_pack(
    const float* __restrict__ Wh_rnn,
    const float* __restrict__ Wq_c, const float* __restrict__ Wk_c,
    const float* __restrict__ Wv_c, const float* __restrict__ Wout_c,
    __half* __restrict__ Wh_p, __half* __restrict__ Wc_p, __half* __restrict__ Wo_p)
{
    int i = blockIdx.x * 256 + threadIdx.x;
    if (i < NH_P) {
        int e = i & 15, t1 = i >> 4;
        int j = t1 & 127, t2 = t1 >> 7;
        int d4 = t2 & 31, r = t2 >> 5;
        int d = 4 * d4 + (e >> 2), g = e & 3;
        Wh_p[i] = __float2half(Wh_rnn[((size_t)r * Hdim + d) * 512 + g * 128 + j]);
    } else if (i < NH_P + NC_P) {
        int ii = i - NH_P;
        int e = ii & 15, t1 = ii >> 4;
        int e4 = t1 % 96, t2 = t1 / 96;
        int d4 = t2 & 31, r = t2 >> 5;
        int d = 4 * d4 + (e >> 2), col = 4 * e4 + (e & 3);
        int mId = col >> 7, colm = col & 127;
        const float* src = (mId == 0 ? Wq_c : (mId == 1 ? Wk_c : Wv_c));
        Wc_p[ii] = __float2half(src[((size_t)r * Hdim + d) * Hdim + colm]);
    } else if (i < NH_P + NC_P + NO_P) {
        int ii = i - NH_P - NC_P;
        int e = ii & 15, t1 = ii >> 4;
        int c4 = t1 & 31, t2 = t1 >> 5;
        int d4 = t2 & 31, r = t2 >> 5;
        int d = 4 * d4 + (e >> 2), col = 4 * c4 + (e & 3);
        Wo_p[ii] = __float2half(Wout_c[((size_t)r * Hdim + d) * Hdim + col]);
    }
}

// 16 MACs: 4 K-values (hq) x 4 cols, weights as 16 halves (two 16B loads)
__device__ __forceinline__ void fma16(float4& acc, const __half* w, const float4 hq) {
    float4 wa = *(const float4*)(w);
    float4 wb = *(const float4*)(w + 8);
    fma16v(acc, wa, wb, hq);
}

// dbuf load/compute macros (chunk = 4 d4-groups = 8 float4), fully static
#define LOADC(BUF, PBASE, CIDX, DSTRIDE)                                          \
    {                                                                             \
        const __half* _b = (PBASE) + (size_t)(CIDX) * 4 * (DSTRIDE);              \
        _Pragma("unroll")                                                         \
        for (int _q = 0; _q < 4; ++_q) {                                          \
            const float4* _p = (const float4*)(_b + (size_t)_q * (DSTRIDE));      \
            BUF[2 * _q] = _p[0]; BUF[2 * _q + 1] = _p[1];                         \
        }                                                                         \
    }
#define FMAC(BUF, ACC, ROWPTR, CIDX)                                              \
    {                                                                             \
        _Pragma("unroll")                                                         \
        for (int _q = 0; _q < 4; ++_q) {                                          \
            float4 _hq = *(const float4*)((ROWPTR) + ((CIDX) * 4 + _q) * 4);      \
            fma16v(ACC, BUF[2 * _q], BUF[2 * _q + 1], _hq);                       \
        }                                                                         \
    }

// ---------------- Kernel 2: sequential scan, one block per batch, 5 barriers/step ----------------
__global__ __launch_bounds__(768) void k_seq(
    const float* __restrict__ statics,
    const float* __restrict__ h0, const float* __restrict__ c0,
    const __half* __restrict__ Wh_p, const __half* __restrict__ Wc_p,
    const __half* __restrict__ Wo_p,
    const float* __restrict__ b_rnn,
    const float* __restrict__ W1, const float* __restrict__ b1,
    const float* __restrict__ W2, const float* __restrict__ b2,
    const float* __restrict__ ghG, const float* __restrict__ WK,
    const float* __restrict__ WB,
    const float* __restrict__ VX32, const __half* __restrict__ VX16, const int m16,
    const float* __restrict__ BX,
    float* __restrict__ out)
{
    const int b = blockIdx.x;
    const int tid = threadIdx.x;
    const int wave = tid >> 6, lane = tid & 63;
    const int r_ = tid >> 7, j_ = tid & 127;

    __shared__ float hs[Rdim][Hdim], cs[Rdim][Hdim], hn[Rdim][Hdim], cn[Rdim][Hdim];
    __shared__ float qc[Rdim][Hdim], kc[Rdim][Hdim], vc[Rdim][Hdim], ctx[Rdim][Hdim];
    __shared__ float BX_s[Rdim][512], brnn_s[Rdim][512];
    __shared__ float WB_s[Rdim][Hdim];
    __shared__ float s0s[8], p0s[8], p1s[8];

    ((float4*)&BX_s[0][0])[tid]   = ((const float4*)BX)[tid];
    ((float4*)&brnn_s[0][0])[tid] = ((const float4*)b_rnn)[tid];
    (&WB_s[0][0])[tid] = WB[tid];

    // per-step data prefetch for t=0
    int bt = b * Tdim;
    float ghr = ghG[(size_t)bt * Hdim + j_];
    float4 vx4;
    if (m16) {
        const __half2* vp = (const __half2*)(VX16 + (((size_t)bt * Rdim + r_) * 128 + j_) * 4);
        float2 a = __half22float2(vp[0]), bb = __half22float2(vp[1]);
        vx4 = make_float4(a.x, a.y, bb.x, bb.y);
    } else {
        vx4 = *(const float4*)(VX32 + (((size_t)bt * Rdim + r_) * 128 + j_) * 4);
    }
    float wk0 = 0.0f, wk1 = 0.0f;
    if (wave < Rdim) {
        wk0 = WK[((size_t)bt * Rdim + wave) * Hdim + lane];
        wk1 = WK[((size_t)bt * Rdim + wave) * Hdim + lane + 64];
    }

    hs[r_][j_] = h0[(size_t)b * 768 + tid] * ghr;
    cs[r_][j_] = c0[(size_t)b * 768 + tid];
    __syncthreads();

    const __half* whp = Wh_p + ((size_t)r_ * 32 * 128 + j_) * 16;   // d4-stride 2048 halves
    float4 wbA[8], wbB[8];

    for (int t = 0; t < Tdim; ++t) {
        bt = b * Tdim + t;
        const bool lastt = (t == Tdim - 1);

        // ==== P0: Wh chunk0 prefetch (all) + scores (waves 0-5) ====
        LOADC(wbA, whp, 0, 2048);
        if (wave < Rdim) {
            float hv0 = hs[wave][lane], hv1 = hs[wave][lane + 64];
            float a0 = hv0 * wk0 + hv1 * wk1;
            float a1 = hv0 * WB_s[wave][lane] + hv1 * WB_s[wave][lane + 64];
            #pragma unroll
            for (int off = 32; off > 0; off >>= 1) {
                a0 += __shfl_xor(a0, off);
                a1 += __shfl_xor(a1, off);
            }
            if (lane == 0) {
                float sv0 = a0 * 0.125f, sv1 = a1 * 0.125f;
                s0s[wave] = sv0;
                float m = fmaxf(sv0, sv1);
                float e0 = expf(sv0 - m), e1 = expf(sv1 - m);
                float inv = 1.0f / (e0 + e1);
                p0s[wave] = e0 * inv; p1s[wave] = e1 * inv;
            }
        }
        __syncthreads();

        // ==== P1: Wh matvec (gate-major, dbuf) + fused LSTM ====
        {
            float4 acc = make_float4(0.f, 0.f, 0.f, 0.f);
            const float* hrow = &hs[r_][0];
            #pragma unroll
            for (int c = 0; c < 8; c += 2) {
                if (c + 1 < 8) LOADC(wbB, whp, c + 1, 2048);
                FMAC(wbA, acc, hrow, c);
                if (c + 2 < 8) LOADC(wbA, whp, c + 2, 2048);
                FMAC(wbB, acc, hrow, c + 1);
            }
            float P0v = p0s[r_], P1v = p1s[r_];
            float ig = acc.x + P0v * vx4.x + P1v * BX_s[r_][j_]       + brnn_s[r_][j_];
            float fg = acc.y + P0v * vx4.y + P1v * BX_s[r_][128 + j_] + brnn_s[r_][128 + j_];
            float gg = acc.z + P0v * vx4.z + P1v * BX_s[r_][256 + j_] + brnn_s[r_][256 + j_];
            float og = acc.w + P0v * vx4.w + P1v * BX_s[r_][384 + j_] + brnn_s[r_][384 + j_];
            float cnew = sigmoidf_(fg) * cs[r_][j_] + sigmoidf_(ig) * tanhf(gg);
            float hnew = sigmoidf_(og) * tanhf(cnew);
            cn[r_][j_] = cnew;
            hn[r_][j_] = hnew;
        }
        __syncthreads();

        // ==== P3: t+1 per-step prefetch (all) + Wc qkv matvec (576 thr, dbuf) ====
        if (!lastt) {
            const int bt1 = bt + 1;
            ghr = ghG[(size_t)bt1 * Hdim + j_];
            if (m16) {
                const __half2* vp = (const __half2*)(VX16 + (((size_t)bt1 * Rdim + r_) * 128 + j_) * 4);
                float2 a = __half22float2(vp[0]), bb = __half22float2(vp[1]);
                vx4 = make_float4(a.x, a.y, bb.x, bb.y);
            } else {
                vx4 = *(const float4*)(VX32 + (((size_t)bt1 * Rdim + r_) * 128 + j_) * 4);
            }
            if (wave < Rdim) {
                wk0 = WK[((size_t)bt1 * Rdim + wave) * Hdim + lane];
                wk1 = WK[((size_t)bt1 * Rdim + wave) * Hdim + lane + 64];
            }
        } else {
            ghr = 1.0f;
        }
        if (tid < 576) {
            const int rG = tid / 96, e4 = tid % 96;
            const __half* wcp = Wc_p + ((size_t)rG * 32 * 96 + e4) * 16;   // d4-stride 1536
            float4 acc = make_float4(0.f, 0.f, 0.f, 0.f);
            const float* hrow = &hn[rG][0];
            LOADC(wbA, wcp, 0, 1536);
            #pragma unroll
            for (int c = 0; c < 8; c += 2) {
                if (c + 1 < 8) LOADC(wbB, wcp, c + 1, 1536);
                FMAC(wbA, acc, hrow, c);
                if (c + 2 < 8) LOADC(wbA, wcp, c + 2, 1536);
                FMAC(wbB, acc, hrow, c + 1);
            }
            int col = e4 * 4, mId = col >> 7, colm = col & 127;
            float* dst = (mId == 0 ? &qc[rG][colm] : (mId == 1 ? &kc[rG][colm] : &vc[rG][colm]));
            *(float4*)dst = acc;
        }
        __syncthreads();

        // ==== P4: attention (tid 512-607, regs) + Wo chunk0 prefetch (tid<192) ====
        if (tid < 192) {
            const int rK = tid / 32, c4 = tid % 32;
            const __half* wop = Wo_p + ((size_t)rK * 32 * 32 + c4) * 16;   // d4-stride 512
            LOADC(wbA, wop, 0, 512);
        } else if (tid >= 512 && tid < 608) {
            const int tl = tid - 512;
            const int rr = tl >> 4, h = (tl >> 2) & 3, q = tl & 3;
            float4 Q[8];
            #pragma unroll
            for (int i = 0; i < 8; ++i) Q[i] = *(const float4*)&qc[rr][h * 32 + 4 * i];
            float sc[Rdim];
            #pragma unroll
            for (int ss = 0; ss < Rdim; ++ss) {
                float acc = 0.0f;
                #pragma unroll
                for (int i = 0; i < 8; ++i) {
                    float4 kq = *(const float4*)&kc[ss][h * 32 + 4 * i];
                    acc += Q[i].x * kq.x + Q[i].y * kq.y + Q[i].z * kq.z + Q[i].w * kq.w;
                }
                sc[ss] = acc * 0.17677669529663687f;
            }
            float m = sc[0];
            #pragma unroll
            for (int ss = 1; ss < Rdim; ++ss) m = fmaxf(m, sc[ss]);
            float e[Rdim], sum = 0.0f;
            #pragma unroll
            for (int ss = 0; ss < Rdim; ++ss) { e[ss] = expf(sc[ss] - m); sum += e[ss]; }
            int rank = 0;
            #pragma unroll
            for (int jj = 0; jj < Rdim; ++jj)
                rank += (s0s[jj] > s0s[rr] || (s0s[jj] == s0s[rr] && jj < rr)) ? 1 : 0;
            float w = ((rank < KACT) ? 1.0f : 0.0f) / sum;
            float4 a0 = make_float4(0.f, 0.f, 0.f, 0.f), a1 = a0;
            #pragma unroll
            for (int ss = 0; ss < Rdim; ++ss) {
                float cl = e[ss] * w;
                float4 v0 = *(const float4*)&vc[ss][h * 32 + q * 8];
                float4 v1 = *(const float4*)&vc[ss][h * 32 + q * 8 + 4];
                a0.x += cl * v0.x; a0.y += cl * v0.y; a0.z += cl * v0.z; a0.w += cl * v0.w;
                a1.x += cl * v1.x; a1.y += cl * v1.y; a1.z += cl * v1.z; a1.w += cl * v1.w;
            }
            *(float4*)&ctx[rr][h * 32 + q * 8] = a0;
            *(float4*)&ctx[rr][h * 32 + q * 8 + 4] = a1;
        }
        __syncthreads();

        // ==== P5: Wout (tid<192, dbuf) + state update + decay(t+1) ====
        if (tid < 192) {
            const int rK = tid / 32, c4 = tid % 32;
            int rankK = 0;
            #pragma unroll
            for (int jj = 0; jj < Rdim; ++jj)
                rankK += (s0s[jj] > s0s[rK] || (s0s[jj] == s0s[rK] && jj < rK)) ? 1 : 0;
            if (rankK < KACT) {
                const __half* wop = Wo_p + ((size_t)rK * 32 * 32 + c4) * 16;
                float4 acc = make_float4(0.f, 0.f, 0.f, 0.f);
                const float* crow = &ctx[rK][0];
                #pragma unroll
                for (int c = 0; c < 8; c += 2) {
                    if (c + 1 < 8) LOADC(wbB, wop, c + 1, 512);
                    FMAC(wbA, acc, crow, c);
                    if (c + 2 < 8) LOADC(wbA, wop, c + 2, 512);
                    FMAC(wbB, acc, crow, c + 1);
                }
                float4 hq = *(const float4*)&hn[rK][c4 * 4];
                float4 g4 = make_float4(1.f, 1.f, 1.f, 1.f);
                if (!lastt) g4 = *(const float4*)&ghG[(size_t)(bt + 1) * Hdim + c4 * 4];
                float4 o;
                o.x = (acc.x + hq.x) * g4.x;
                o.y = (acc.y + hq.y) * g4.y;
                o.z = (acc.z + hq.z) * g4.z;
                o.w = (acc.w + hq.w) * g4.w;
                *(float4*)&hs[rK][c4 * 4] = o;
            }
        }
        {
            int rank = 0;
            #pragma unroll
            for (int jj = 0; jj < Rdim; ++jj)
                rank += (s0s[jj] > s0s[r_] || (s0s[jj] == s0s[r_] && jj < r_)) ? 1 : 0;
            if (rank < KACT) cs[r_][j_] = cn[r_][j_];
            else             hs[r_][j_] *= ghr;     // inactive: keep decayed h_old
        }
        __syncthreads();
    }

    // Head
    if (tid < 64) {
        float a = b1[tid];
        const float* hsf = &hs[0][0];
        #pragma unroll 4
        for (int i = 0; i < Rdim * Hdim; ++i) a += hsf[i] * W1[i * 64 + tid];
        #pragma unroll
        for (int i = 0; i < Sdim; ++i) a += statics[b * Sdim + i] * W1[(Rdim * Hdim + i) * 64 + tid];
        float pv = a * W2[tid];
        #pragma unroll
        for (int off = 32; off > 0; off >>= 1) pv += __shfl_xor(pv, off);
        if (tid == 0) out[b] = pv + b2[0];
    }
}

extern "C" void kernel_launch(void* const* d_in, const int* in_sizes, int n_in,
                              void* d_out, int out_size, void* d_ws, size_t ws_size,
                              hipStream_t stream) {
    const float* x       = (const float*)d_in[0];
    const float* statics = (const float*)d_in[1];
    const float* mask    = (const float*)d_in[2];
    const float* delta   = (const float*)d_in[3];
    const float* xlast   = (const float*)d_in[4];
    const float* xmean   = (const float*)d_in[5];
    const float* h0      = (const float*)d_in[6];
    const float* c0      = (const float*)d_in[7];
    const float* Wgx     = (const float*)d_in[8];
    const float* bgx     = (const float*)d_in[9];
    const float* Wgh     = (const float*)d_in[10];
    const float* bgh     = (const float*)d_in[11];
    const float* Wk_in   = (const float*)d_in[12];
    const float* bk_in   = (const float*)d_in[13];
    const float* Wv_in   = (const float*)d_in[14];
    const float* bv_in   = (const float*)d_in[15];
    const float* Wq_in   = (const float*)d_in[16];
    const float* Wx_rnn  = (const float*)d_in[17];
    const float* Wh_rnn  = (const float*)d_in[18];
    const float* b_rnn   = (const float*)d_in[19];
    const float* Wq_c    = (const float*)d_in[20];
    const float* Wk_c    = (const float*)d_in[21];
    const float* Wv_c    = (const float*)d_in[22];
    const float* Wout_c  = (const float*)d_in[23];
    const float* W1      = (const float*)d_in[24];
    const float* b1      = (const float*)d_in[25];
    const float* W2      = (const float*)d_in[26];
    const float* b2      = (const float*)d_in[27];

    const size_t nGh  = (size_t)Bdim * Tdim * Hdim;
    const size_t nK   = (size_t)Bdim * Tdim * DK;
    const size_t nV   = (size_t)Bdim * Tdim * DV;
    const size_t nBX  = (size_t)Rdim * 512;
    const size_t nWB  = (size_t)Rdim * Hdim;
    const size_t nWK  = (size_t)Bdim * Tdim * Rdim * Hdim;
    const size_t nPck = (size_t)(NH_P + NC_P + NO_P) / 2;
    const size_t nVX  = (size_t)Bdim * Tdim * Rdim * 512;

    float*  ws   = (float*)d_ws;
    float*  ghG  = ws;
    float*  kG   = ghG + nGh;
    float*  vG   = kG + nK;
    float*  BX   = vG + nV;
    float*  WB   = BX + nBX;
    float*  WK   = WB + nWB;
    __half* Wh_p = (__half*)(WK + nWK);
    __half* Wc_p = Wh_p + NH_P;
    __half* Wo_p = Wc_p + NC_P;
    float*  VXf  = WK + nWK + nPck;
    __half* VXh  = (__half*)VXf;

    const size_t base = nGh + nK + nV + nBX + nWB + nWK + nPck;
    const int m16 = (ws_size >= (base + nVX) * sizeof(float)) ? 0 : 1;

    k_pre<<<dim3(Bdim * Tdim), dim3(128), 0, stream>>>(
        x, mask, delta, xlast, xmean, Wgx, bgx, Wgh, bgh,
        Wk_in, bk_in, Wv_in, bv_in, ghG, kG, vG);

    k_bx<<<dim3((Rdim * 512 + Rdim * Hdim + 255) / 256), dim3(256), 0, stream>>>(
        bv_in, Wx_rnn, bk_in, Wq_in, BX, WB);

    k_wk<<<dim3(Bdim * Tdim / 32, Rdim), dim3(256), 0, stream>>>(kG, Wq_in, WK);

    k_pack<<<dim3((NH_P + NC_P + NO_P + 255) / 256), dim3(256), 0, stream>>>(
        Wh_rnn, Wq_c, Wk_c, Wv_c, Wout_c, Wh_p, Wc_p, Wo_p);

    k_vx<<<dim3(Bdim * Tdim / VX_BT, Rdim, 4), dim3(256), 0, stream>>>(
        vG, Wx_rnn, VXf, VXh, m16);

    k_seq<<<dim3(Bdim), dim3(768), 0, stream>>>(
        statics, h0, c0, Wh_p, Wc_p, Wo_p, b_rnn,
        W1, b1, W2, b2, ghG, WK, WB, VXf, VXh, m16, BX, (float*)d_out);
}

// Round 11
// 2595.497 us; speedup vs baseline: 9.2317x; 8.2889x over previous
//
#include <hip/hip_runtime.h>
#include <hip/hip_bf16.h>
#include <hip/hip_fp16.h>
#include <math.h>

#define Bdim 128
#define Tdim 96
#define Fdim 64
#define Sdim 16
#define Rdim 6
#define KACT 4
#define Hdim 128
#define DK 64
#define DV 128
#define HC 4
#define CK 32
#define CV 32

__device__ __forceinline__ float sigmoidf_(float x) { return 1.0f / (1.0f + expf(-x)); }

// ---------------- Kernel 1: precompute gamma_h, k, v for all (b,t) ----------------
__global__ __launch_bounds__(128) void k_pre(
    const float* __restrict__ x, const float* __restrict__ mask,
    const float* __restrict__ delta, const float* __restrict__ xlast,
    const float* __restrict__ xmean,
    const float* __restrict__ Wgx, const float* __restrict__ bgx,
    const float* __restrict__ Wgh, const float* __restrict__ bgh,
    const float* __restrict__ Wk, const float* __restrict__ bk,
    const float* __restrict__ Wv, const float* __restrict__ bv,
    float* __restrict__ ghO, float* __restrict__ kO, float* __restrict__ vO)
{
    const int bt = blockIdx.x;
    const int b = bt / Tdim, t = bt % Tdim;
    const int tid = threadIdx.x;
    __shared__ float d_s[Fdim], xh_s[Fdim];
    const int base = (b * Tdim + t) * Fdim;

    if (tid < Fdim) d_s[tid] = delta[base + tid];
    __syncthreads();

    if (tid < Fdim) {
        float z = bgx[tid];
        #pragma unroll 8
        for (int i = 0; i < Fdim; ++i) z += d_s[i] * Wgx[i * Fdim + tid];
        float gx = expf(-fmaxf(z, 0.0f));
        float m = mask[base + tid], xv = x[base + tid];
        float xl = xlast[base + tid], xm = xmean[b * Fdim + tid];
        xh_s[tid] = m * xv + (1.0f - m) * (gx * xl + (1.0f - gx) * xm);
    }
    {
        float z = bgh[tid];
        #pragma unroll 8
        for (int i = 0; i < Fdim; ++i) z += d_s[i] * Wgh[i * Hdim + tid];
        ghO[(size_t)(b * Tdim + t) * Hdim + tid] = expf(-fmaxf(z, 0.0f));
    }
    __syncthreads();

    if (tid < DK) {
        float z = bk[tid];
        #pragma unroll 8
        for (int j = 0; j < Fdim; ++j) z += xh_s[j] * Wk[j * DK + tid];
        kO[(size_t)(b * Tdim + t) * DK + tid] = z;
    }
    {
        float z = bv[tid];
        #pragma unroll 8
        for (int j = 0; j < Fdim; ++j) z += xh_s[j] * Wv[j * DV + tid];
        vO[(size_t)(b * Tdim + t) * DV + tid] = z;
    }
}

// ---------------- Kernel 1b: BX[r,c] = bv @ Wx_rnn[r];  WB[r,h] = Wq_in[r,h,:]·bk ----------------
__global__ __launch_bounds__(256) void k_bx(
    const float* __restrict__ bv, const float* __restrict__ Wx_rnn,
    const float* __restrict__ bk, const float* __restrict__ Wq_in,
    float* __restrict__ BX, float* __restrict__ WB)
{
    int c = blockIdx.x * 256 + threadIdx.x;
    if (c < Rdim * 512) {
        int r = c >> 9, cc = c & 511;
        float acc = 0.0f;
        #pragma unroll 4
        for (int d = 0; d < DV; ++d)
            acc += bv[d] * Wx_rnn[((size_t)r * DV + d) * 512 + cc];
        BX[c] = acc;
    } else if (c < Rdim * 512 + Rdim * Hdim) {
        int i = c - Rdim * 512;
        int r = i >> 7, h = i & 127;
        float acc = 0.0f;
        #pragma unroll 8
        for (int d = 0; d < DK; ++d)
            acc += Wq_in[((size_t)r * Hdim + h) * DK + d] * bk[d];
        WB[i] = acc;
    }
}

// ---------------- Kernel 1c: VX gate-major: VX[bt][r][j][g] = v[bt,:]·Wx[r][:, g*128+j] ----------------
#define VX_BT 32
__global__ __launch_bounds__(256) void k_vx(
    const float* __restrict__ vG, const float* __restrict__ Wx_rnn,
    float* __restrict__ VX32, __half* __restrict__ VX16, const int m16)
{
    const int bt0 = blockIdx.x * VX_BT;
    const int r = blockIdx.y;
    const int g = blockIdx.z;                 // gate 0..3
    const int j = threadIdx.x & 127;
    const int c = g * 128 + j;
    const int half_ = threadIdx.x >> 7;
    __shared__ float vv_s[VX_BT][DV];

    for (int i = threadIdx.x; i < VX_BT * DV; i += 256)
        vv_s[i >> 7][i & 127] = vG[(size_t)(bt0 + (i >> 7)) * DV + (i & 127)];
    __syncthreads();

    float acc[16];
    #pragma unroll
    for (int i = 0; i < 16; ++i) acc[i] = 0.0f;

    const float* wp = Wx_rnn + ((size_t)r * DV) * 512 + c;
    const int btb = half_ * 16;
    #pragma unroll 4
    for (int d = 0; d < DV; ++d) {
        float w = wp[(size_t)d * 512];
        #pragma unroll
        for (int i = 0; i < 16; ++i) acc[i] += vv_s[btb + i][d] * w;
    }
    #pragma unroll
    for (int i = 0; i < 16; ++i) {
        size_t idx = (((size_t)(bt0 + btb + i) * Rdim + r) * 128 + j) * 4 + g;
        if (m16) VX16[idx] = __float2half(acc[i]);
        else     VX32[idx] = acc[i];
    }
}

// ---------------- Kernel 1d: WK[bt,r,h] = Wq_in[r,h,:] · k[bt,:] ----------------
__global__ __launch_bounds__(256) void k_wk(
    const float* __restrict__ kG, const float* __restrict__ Wq_in,
    float* __restrict__ WK)
{
    const int bt0 = blockIdx.x * 32;
    const int r = blockIdx.y;
    __shared__ float ks[32][66];
    for (int e = threadIdx.x; e < 32 * 64; e += 256)
        ks[e >> 6][e & 63] = kG[(size_t)(bt0 + (e >> 6)) * DK + (e & 63)];
    __syncthreads();

    const int btl = threadIdx.x >> 3, hg = threadIdx.x & 7;
    const float* wq = Wq_in + (size_t)r * Hdim * DK;
    #pragma unroll 4
    for (int i = 0; i < 16; ++i) {
        int h = hg + i * 8;
        const float4* wr = (const float4*)(wq + (size_t)h * DK);
        float acc = 0.0f;
        #pragma unroll
        for (int d4 = 0; d4 < 16; ++d4) {
            float4 w = wr[d4];
            acc += w.x * ks[btl][d4 * 4] + w.y * ks[btl][d4 * 4 + 1]
                 + w.z * ks[btl][d4 * 4 + 2] + w.w * ks[btl][d4 * 4 + 3];
        }
        WK[((size_t)(bt0 + btl) * Rdim + r) * Hdim + h] = acc;
    }
}

// ---------------- Kernel 1e: fp16-pack hot weights, {4 K x 4 cols} per 32B group ----------------
// Wh_p [r][d4<32][c4<128][16] <- Wh_rnn[r][128][512]
// Wc_p [r][d4<32][e4<96][16]  <- [Wq_c|Wk_c|Wv_c][r][128][128] (cols 0..383)
// Wo_p [r][d4<32][c4<32][16]  <- Wout_c[r][128][128]
// group idx j<16: d = 4*d4 + (j>>2), col = 4*c4 + (j&3)
#define NH_P (Rdim * 32 * 128 * 16)
#define NC_P (Rdim * 32 * 96 * 16)
#define NO_P (Rdim * 32 * 32 * 16)
__global__ __launch_bounds__(256) void k_pack(
    const float* __restrict__ Wh_rnn,
    const float* __restrict__ Wq_c, const float* __restrict__ Wk_c,
    const float* __restrict__ Wv_c, const float* __restrict__ Wout_c,
    __half* __restrict__ Wh_p, __half* __restrict__ Wc_p, __half* __restrict__ Wo_p)
{
    int i = blockIdx.x * 256 + threadIdx.x;
    if (i < NH_P) {
        int j = i & 15, t1 = i >> 4;
        int c4 = t1 & 127, t2 = t1 >> 7;
        int d4 = t2 & 31, r = t2 >> 5;
        int d = 4 * d4 + (j >> 2), col = 4 * c4 + (j & 3);
        Wh_p[i] = __float2half(Wh_rnn[((size_t)r * Hdim + d) * 512 + col]);
    } else if (i < NH_P + NC_P) {
        int ii = i - NH_P;
        int j = ii & 15, t1 = ii >> 4;
        int e4 = t1 % 96, t2 = t1 / 96;
        int d4 = t2 & 31, r = t2 >> 5;
        int d = 4 * d4 + (j >> 2), col = 4 * e4 + (j & 3);
        int mId = col >> 7, colm = col & 127;
        const float* src = (mId == 0 ? Wq_c : (mId == 1 ? Wk_c : Wv_c));
        Wc_p[ii] = __float2half(src[((size_t)r * Hdim + d) * Hdim + colm]);
    } else if (i < NH_P + NC_P + NO_P) {
        int ii = i - NH_P - NC_P;
        int j = ii & 15, t1 = ii >> 4;
        int c4 = t1 & 31, t2 = t1 >> 5;
        int d4 = t2 & 31, r = t2 >> 5;
        int d = 4 * d4 + (j >> 2), col = 4 * c4 + (j & 3);
        Wo_p[ii] = __float2half(Wout_c[((size_t)r * Hdim + d) * Hdim + col]);
    }
}

// 16 MACs: 4 K-values (hq) x 4 cols, weights as 16 halves (two 16B loads)
__device__ __forceinline__ void fma16(float4& acc, const __half* w, const float4 hq) {
    float4 wa = *(const float4*)(w);
    float4 wb = *(const float4*)(w + 8);
    const __half2* ha = (const __half2*)&wa;
    const __half2* hb = (const __half2*)&wb;
    float2 c;
    c = __half22float2(ha[0]); acc.x += hq.x * c.x; acc.y += hq.x * c.y;
    c = __half22float2(ha[1]); acc.z += hq.x * c.x; acc.w += hq.x * c.y;
    c = __half22float2(ha[2]); acc.x += hq.y * c.x; acc.y += hq.y * c.y;
    c = __half22float2(ha[3]); acc.z += hq.y * c.x; acc.w += hq.y * c.y;
    c = __half22float2(hb[0]); acc.x += hq.z * c.x; acc.y += hq.z * c.y;
    c = __half22float2(hb[1]); acc.z += hq.z * c.x; acc.w += hq.z * c.y;
    c = __half22float2(hb[2]); acc.x += hq.w * c.x; acc.y += hq.w * c.y;
    c = __half22float2(hb[3]); acc.z += hq.w * c.x; acc.w += hq.w * c.y;
}

// ---------------- Kernel 2: sequential scan, one block per batch, 5 barriers/step ----------------
__global__ __launch_bounds__(768) void k_seq(
    const float* __restrict__ statics,
    const float* __restrict__ h0, const float* __restrict__ c0,
    const __half* __restrict__ Wh_p, const __half* __restrict__ Wc_p,
    const __half* __restrict__ Wo_p,
    const float* __restrict__ b_rnn,
    const float* __restrict__ W1, const float* __restrict__ b1,
    const float* __restrict__ W2, const float* __restrict__ b2,
    const float* __restrict__ ghG, const float* __restrict__ WK,
    const float* __restrict__ WB,
    const float* __restrict__ VX32, const __half* __restrict__ VX16, const int m16,
    const float* __restrict__ BX,
    float* __restrict__ out)
{
    const int b = blockIdx.x;
    const int tid = threadIdx.x;
    const int wave = tid >> 6, lane = tid & 63;
    const int r_ = tid >> 7, j_ = tid & 127;

    __shared__ float hs[Rdim][Hdim], cs[Rdim][Hdim], hn[Rdim][Hdim], cn[Rdim][Hdim];
    __shared__ float pre_s[Rdim][4 * Hdim];
    __shared__ float qc[Rdim][Hdim], kc[Rdim][Hdim], vc[Rdim][Hdim], ctx[Rdim][Hdim];
    __shared__ float BX_s[Rdim][512], brnn_s[Rdim][512];
    __shared__ float WB_s[Rdim][Hdim];
    __shared__ float s0s[8], p0s[8], p1s[8], mk[8];

    // preload per-model constants into LDS (once)
    ((float4*)&BX_s[0][0])[tid]   = ((const float4*)BX)[tid];
    ((float4*)&brnn_s[0][0])[tid] = ((const float4*)b_rnn)[tid];
    (&WB_s[0][0])[tid] = WB[tid];

    // per-step data prefetch for t=0
    int bt = b * Tdim;
    float ghr = ghG[(size_t)bt * Hdim + j_];
    float4 vx4;
    if (m16) {
        const __half2* vp = (const __half2*)(VX16 + (((size_t)bt * Rdim + r_) * 128 + j_) * 4);
        float2 a = __half22float2(vp[0]), bb = __half22float2(vp[1]);
        vx4 = make_float4(a.x, a.y, bb.x, bb.y);
    } else {
        vx4 = *(const float4*)(VX32 + (((size_t)bt * Rdim + r_) * 128 + j_) * 4);
    }
    float wk0 = 0.0f, wk1 = 0.0f;
    if (wave < Rdim) {
        wk0 = WK[((size_t)bt * Rdim + wave) * Hdim + lane];
        wk1 = WK[((size_t)bt * Rdim + wave) * Hdim + lane + 64];
    }

    // init carry with decay(t=0) folded in
    hs[r_][j_] = h0[(size_t)b * 768 + tid] * ghr;
    cs[r_][j_] = c0[(size_t)b * 768 + tid];
    __syncthreads();

    for (int t = 0; t < Tdim; ++t) {
        bt = b * Tdim + t;
        const bool lastt = (t == Tdim - 1);

        // ==== phase 1: B scores (waves 0-5) in parallel with E = hs @ Wh (all waves)
        if (wave < Rdim) {
            float hv0 = hs[wave][lane], hv1 = hs[wave][lane + 64];
            float a0 = hv0 * wk0 + hv1 * wk1;
            float a1 = hv0 * WB_s[wave][lane] + hv1 * WB_s[wave][lane + 64];
            #pragma unroll
            for (int off = 32; off > 0; off >>= 1) {
                a0 += __shfl_xor(a0, off);
                a1 += __shfl_xor(a1, off);
            }
            if (lane == 0) {
                float sv0 = a0 * 0.125f, sv1 = a1 * 0.125f;
                s0s[wave] = sv0;
                float m = fmaxf(sv0, sv1);
                float e0 = expf(sv0 - m), e1 = expf(sv1 - m);
                float inv = 1.0f / (e0 + e1);
                p0s[wave] = e0 * inv; p1s[wave] = e1 * inv;
            }
        }
        {
            float4 acc = make_float4(0.f, 0.f, 0.f, 0.f);
            const __half* wp = Wh_p + (((size_t)r_ * 32) * 128 + j_) * 16;
            #pragma unroll 8
            for (int d4 = 0; d4 < 32; ++d4) {
                float4 hq = *(const float4*)&hs[r_][d4 * 4];
                fma16(acc, wp, hq);
                wp += 128 * 16;
            }
            *(float4*)&pre_s[r_][j_ * 4] = acc;
        }
        __syncthreads();

        // ==== phase 2: top-k mask (6 thr) + LSTM with fused bias/VX/BX (all)
        if (tid < Rdim) {
            int rank = 0;
            #pragma unroll
            for (int j = 0; j < Rdim; ++j)
                rank += (s0s[j] > s0s[tid] || (s0s[j] == s0s[tid] && j < tid)) ? 1 : 0;
            mk[tid] = (rank < KACT) ? 1.0f : 0.0f;
        }
        {
            float P0v = p0s[r_], P1v = p1s[r_];
            float ig = pre_s[r_][j_]       + P0v * vx4.x + P1v * BX_s[r_][j_]       + brnn_s[r_][j_];
            float fg = pre_s[r_][128 + j_] + P0v * vx4.y + P1v * BX_s[r_][128 + j_] + brnn_s[r_][128 + j_];
            float gg = pre_s[r_][256 + j_] + P0v * vx4.z + P1v * BX_s[r_][256 + j_] + brnn_s[r_][256 + j_];
            float og = pre_s[r_][384 + j_] + P0v * vx4.w + P1v * BX_s[r_][384 + j_] + brnn_s[r_][384 + j_];
            float cnew = sigmoidf_(fg) * cs[r_][j_] + sigmoidf_(ig) * tanhf(gg);
            float hnew = sigmoidf_(og) * tanhf(cnew);
            cn[r_][j_] = cnew;
            hn[r_][j_] = hnew;
        }
        __syncthreads();

        // ==== phase 3: register-prefetch t+1 (all) + G qkv matvec (576 thr)
        if (!lastt) {
            const int bt1 = bt + 1;
            ghr = ghG[(size_t)bt1 * Hdim + j_];
            if (m16) {
                const __half2* vp = (const __half2*)(VX16 + (((size_t)bt1 * Rdim + r_) * 128 + j_) * 4);
                float2 a = __half22float2(vp[0]), bb = __half22float2(vp[1]);
                vx4 = make_float4(a.x, a.y, bb.x, bb.y);
            } else {
                vx4 = *(const float4*)(VX32 + (((size_t)bt1 * Rdim + r_) * 128 + j_) * 4);
            }
            if (wave < Rdim) {
                wk0 = WK[((size_t)bt1 * Rdim + wave) * Hdim + lane];
                wk1 = WK[((size_t)bt1 * Rdim + wave) * Hdim + lane + 64];
            }
        } else {
            ghr = 1.0f;
        }
        if (tid < 576) {
            const int rG = tid / 96, e4 = tid % 96;
            float4 acc = make_float4(0.f, 0.f, 0.f, 0.f);
            const __half* wp = Wc_p + (((size_t)rG * 32) * 96 + e4) * 16;
            #pragma unroll 8
            for (int d4 = 0; d4 < 32; ++d4) {
                float4 hq = *(const float4*)&hn[rG][d4 * 4];
                fma16(acc, wp, hq);
                wp += 96 * 16;
            }
            int col = e4 * 4, mId = col >> 7, colm = col & 127;
            float* dst = (mId == 0 ? &qc[rG][colm] : (mId == 1 ? &kc[rG][colm] : &vc[rG][colm]));
            *(float4*)dst = acc;
        }
        __syncthreads();

        // ==== phase 4: fused attention scores + softmax + ctx (96 thr, all in regs)
        if (tid < 96) {
            int rr = tid >> 4, h = (tid >> 2) & 3, q = tid & 3;
            float4 Q[8];
            #pragma unroll
            for (int i = 0; i < 8; ++i) Q[i] = *(const float4*)&qc[rr][h * 32 + 4 * i];
            float sc[Rdim];
            #pragma unroll
            for (int ss = 0; ss < Rdim; ++ss) {
                float acc = 0.0f;
                #pragma unroll
                for (int i = 0; i < 8; ++i) {
                    float4 kq = *(const float4*)&kc[ss][h * 32 + 4 * i];
                    acc += Q[i].x * kq.x + Q[i].y * kq.y + Q[i].z * kq.z + Q[i].w * kq.w;
                }
                sc[ss] = acc * 0.17677669529663687f;
            }
            float m = sc[0];
            #pragma unroll
            for (int ss = 1; ss < Rdim; ++ss) m = fmaxf(m, sc[ss]);
            float e[Rdim], sum = 0.0f;
            #pragma unroll
            for (int ss = 0; ss < Rdim; ++ss) { e[ss] = expf(sc[ss] - m); sum += e[ss]; }
            float w = mk[rr] / sum;
            float4 a0 = make_float4(0.f, 0.f, 0.f, 0.f), a1 = a0;
            #pragma unroll
            for (int ss = 0; ss < Rdim; ++ss) {
                float cl = e[ss] * w;
                float4 v0 = *(const float4*)&vc[ss][h * 32 + q * 8];
                float4 v1 = *(const float4*)&vc[ss][h * 32 + q * 8 + 4];
                a0.x += cl * v0.x; a0.y += cl * v0.y; a0.z += cl * v0.z; a0.w += cl * v0.w;
                a1.x += cl * v1.x; a1.y += cl * v1.y; a1.z += cl * v1.z; a1.w += cl * v1.w;
            }
            *(float4*)&ctx[rr][h * 32 + q * 8] = a0;
            *(float4*)&ctx[rr][h * 32 + q * 8 + 4] = a1;
        }
        __syncthreads();

        // ==== phase 5: Wout matvec + state update + decay(t+1) folded in
        if (tid < 192) {
            const int rK = tid / 32, c4 = tid % 32;
            if (mk[rK] > 0.5f) {
                float4 acc = make_float4(0.f, 0.f, 0.f, 0.f);
                const __half* wp = Wo_p + (((size_t)rK * 32) * 32 + c4) * 16;
                #pragma unroll 8
                for (int d4 = 0; d4 < 32; ++d4) {
                    float4 cq = *(const float4*)&ctx[rK][d4 * 4];
                    fma16(acc, wp, cq);
                    wp += 32 * 16;
                }
                float4 hq = *(const float4*)&hn[rK][c4 * 4];
                float4 g4 = make_float4(1.f, 1.f, 1.f, 1.f);
                if (!lastt) g4 = *(const float4*)&ghG[(size_t)(bt + 1) * Hdim + c4 * 4];
                float4 o;
                o.x = (acc.x + hq.x) * g4.x;
                o.y = (acc.y + hq.y) * g4.y;
                o.z = (acc.z + hq.z) * g4.z;
                o.w = (acc.w + hq.w) * g4.w;
                *(float4*)&hs[rK][c4 * 4] = o;
            }
        }
        {
            if (mk[r_] > 0.5f) cs[r_][j_] = cn[r_][j_];
            else               hs[r_][j_] *= ghr;   // inactive row: keep decayed h_old
        }
        __syncthreads();
    }

    // Head: out[b] = (concat(hs, statics) @ W1 + b1) @ W2 + b2
    if (tid < 64) {
        float a = b1[tid];
        const float* hsf = &hs[0][0];
        #pragma unroll 4
        for (int i = 0; i < Rdim * Hdim; ++i) a += hsf[i] * W1[i * 64 + tid];
        #pragma unroll
        for (int i = 0; i < Sdim; ++i) a += statics[b * Sdim + i] * W1[(Rdim * Hdim + i) * 64 + tid];
        float pv = a * W2[tid];
        #pragma unroll
        for (int off = 32; off > 0; off >>= 1) pv += __shfl_xor(pv, off);
        if (tid == 0) out[b] = pv + b2[0];
    }
}

extern "C" void kernel_launch(void* const* d_in, const int* in_sizes, int n_in,
                              void* d_out, int out_size, void* d_ws, size_t ws_size,
                              hipStream_t stream) {
    const float* x       = (const float*)d_in[0];
    const float* statics = (const float*)d_in[1];
    const float* mask    = (const float*)d_in[2];
    const float* delta   = (const float*)d_in[3];
    const float* xlast   = (const float*)d_in[4];
    const float* xmean   = (const float*)d_in[5];
    const float* h0      = (const float*)d_in[6];
    const float* c0      = (const float*)d_in[7];
    const float* Wgx     = (const float*)d_in[8];
    const float* bgx     = (const float*)d_in[9];
    const float* Wgh     = (const float*)d_in[10];
    const float* bgh     = (const float*)d_in[11];
    const float* Wk_in   = (const float*)d_in[12];
    const float* bk_in   = (const float*)d_in[13];
    const float* Wv_in   = (const float*)d_in[14];
    const float* bv_in   = (const float*)d_in[15];
    const float* Wq_in   = (const float*)d_in[16];
    const float* Wx_rnn  = (const float*)d_in[17];
    const float* Wh_rnn  = (const float*)d_in[18];
    const float* b_rnn   = (const float*)d_in[19];
    const float* Wq_c    = (const float*)d_in[20];
    const float* Wk_c    = (const float*)d_in[21];
    const float* Wv_c    = (const float*)d_in[22];
    const float* Wout_c  = (const float*)d_in[23];
    const float* W1      = (const float*)d_in[24];
    const float* b1      = (const float*)d_in[25];
    const float* W2      = (const float*)d_in[26];
    const float* b2      = (const float*)d_in[27];

    const size_t nGh  = (size_t)Bdim * Tdim * Hdim;
    const size_t nK   = (size_t)Bdim * Tdim * DK;
    const size_t nV   = (size_t)Bdim * Tdim * DV;
    const size_t nBX  = (size_t)Rdim * 512;
    const size_t nWB  = (size_t)Rdim * Hdim;
    const size_t nWK  = (size_t)Bdim * Tdim * Rdim * Hdim;
    const size_t nPck = (size_t)(NH_P + NC_P + NO_P) / 2;
    const size_t nVX  = (size_t)Bdim * Tdim * Rdim * 512;

    float*  ws   = (float*)d_ws;
    float*  ghG  = ws;
    float*  kG   = ghG + nGh;
    float*  vG   = kG + nK;
    float*  BX   = vG + nV;
    float*  WB   = BX + nBX;
    float*  WK   = WB + nWB;
    __half* Wh_p = (__half*)(WK + nWK);
    __half* Wc_p = Wh_p + NH_P;
    __half* Wo_p = Wc_p + NC_P;
    float*  VXf  = WK + nWK + nPck;
    __half* VXh  = (__half*)VXf;

    const size_t base = nGh + nK + nV + nBX + nWB + nWK + nPck;
    const int m16 = (ws_size >= (base + nVX) * sizeof(float)) ? 0 : 1;

    k_pre<<<dim3(Bdim * Tdim), dim3(128), 0, stream>>>(
        x, mask, delta, xlast, xmean, Wgx, bgx, Wgh, bgh,
        Wk_in, bk_in, Wv_in, bv_in, ghG, kG, vG);

    k_bx<<<dim3((Rdim * 512 + Rdim * Hdim + 255) / 256), dim3(256), 0, stream>>>(
        bv_in, Wx_rnn, bk_in, Wq_in, BX, WB);

    k_wk<<<dim3(Bdim * Tdim / 32, Rdim), dim3(256), 0, stream>>>(kG, Wq_in, WK);

    k_pack<<<dim3((NH_P + NC_P + NO_P + 255) / 256), dim3(256), 0, stream>>>(
        Wh_rnn, Wq_c, Wk_c, Wv_c, Wout_c, Wh_p, Wc_p, Wo_p);

    k_vx<<<dim3(Bdim * Tdim / VX_BT, Rdim, 4), dim3(256), 0, stream>>>(
        vG, Wx_rnn, VXf, VXh, m16);

    k_seq<<<dim3(Bdim), dim3(768), 0, stream>>>(
        statics, h0, c0, Wh_p, Wc_p, Wo_p, b_rnn,
        W1, b1, W2, b2, ghG, WK, WB, VXf, VXh, m16, BX, (float*)d_out);
}

// Round 12
// 2357.104 us; speedup vs baseline: 10.1654x; 1.1011x over previous
//
#include <hip/hip_runtime.h>
#include <hip/hip_bf16.h>
#include <hip/hip_fp16.h>
#include <math.h>

#define Bdim 128
#define Tdim 96
#define Fdim 64
#define Sdim 16
#define Rdim 6
#define KACT 4
#define Hdim 128
#define DK 64
#define DV 128
#define HC 4
#define CK 32
#define CV 32

__device__ __forceinline__ float sigmoidf_(float x) { return 1.0f / (1.0f + expf(-x)); }

// ---------------- Kernel 1: precompute gamma_h, k, v for all (b,t) ----------------
__global__ __launch_bounds__(128) void k_pre(
    const float* __restrict__ x, const float* __restrict__ mask,
    const float* __restrict__ delta, const float* __restrict__ xlast,
    const float* __restrict__ xmean,
    const float* __restrict__ Wgx, const float* __restrict__ bgx,
    const float* __restrict__ Wgh, const float* __restrict__ bgh,
    const float* __restrict__ Wk, const float* __restrict__ bk,
    const float* __restrict__ Wv, const float* __restrict__ bv,
    float* __restrict__ ghO, float* __restrict__ kO, float* __restrict__ vO)
{
    const int bt = blockIdx.x;
    const int b = bt / Tdim, t = bt % Tdim;
    const int tid = threadIdx.x;
    __shared__ float d_s[Fdim], xh_s[Fdim];
    const int base = (b * Tdim + t) * Fdim;

    if (tid < Fdim) d_s[tid] = delta[base + tid];
    __syncthreads();

    if (tid < Fdim) {
        float z = bgx[tid];
        #pragma unroll 8
        for (int i = 0; i < Fdim; ++i) z += d_s[i] * Wgx[i * Fdim + tid];
        float gx = expf(-fmaxf(z, 0.0f));
        float m = mask[base + tid], xv = x[base + tid];
        float xl = xlast[base + tid], xm = xmean[b * Fdim + tid];
        xh_s[tid] = m * xv + (1.0f - m) * (gx * xl + (1.0f - gx) * xm);
    }
    {
        float z = bgh[tid];
        #pragma unroll 8
        for (int i = 0; i < Fdim; ++i) z += d_s[i] * Wgh[i * Hdim + tid];
        ghO[(size_t)(b * Tdim + t) * Hdim + tid] = expf(-fmaxf(z, 0.0f));
    }
    __syncthreads();

    if (tid < DK) {
        float z = bk[tid];
        #pragma unroll 8
        for (int j = 0; j < Fdim; ++j) z += xh_s[j] * Wk[j * DK + tid];
        kO[(size_t)(b * Tdim + t) * DK + tid] = z;
    }
    {
        float z = bv[tid];
        #pragma unroll 8
        for (int j = 0; j < Fdim; ++j) z += xh_s[j] * Wv[j * DV + tid];
        vO[(size_t)(b * Tdim + t) * DV + tid] = z;
    }
}

// ---------------- Kernel 1b: BX[r,c] = bv @ Wx_rnn[r];  WB[r,h] = Wq_in[r,h,:]·bk ----------------
__global__ __launch_bounds__(256) void k_bx(
    const float* __restrict__ bv, const float* __restrict__ Wx_rnn,
    const float* __restrict__ bk, const float* __restrict__ Wq_in,
    float* __restrict__ BX, float* __restrict__ WB)
{
    int c = blockIdx.x * 256 + threadIdx.x;
    if (c < Rdim * 512) {
        int r = c >> 9, cc = c & 511;
        float acc = 0.0f;
        #pragma unroll 4
        for (int d = 0; d < DV; ++d)
            acc += bv[d] * Wx_rnn[((size_t)r * DV + d) * 512 + cc];
        BX[c] = acc;
    } else if (c < Rdim * 512 + Rdim * Hdim) {
        int i = c - Rdim * 512;
        int r = i >> 7, h = i & 127;
        float acc = 0.0f;
        #pragma unroll 8
        for (int d = 0; d < DK; ++d)
            acc += Wq_in[((size_t)r * Hdim + h) * DK + d] * bk[d];
        WB[i] = acc;
    }
}

// ---------------- Kernel 1c: VX gate-major: VX[bt][r][j][g] = v[bt,:]·Wx[r][:, g*128+j] ----------------
#define VX_BT 32
__global__ __launch_bounds__(256) void k_vx(
    const float* __restrict__ vG, const float* __restrict__ Wx_rnn,
    float* __restrict__ VX32, __half* __restrict__ VX16, const int m16)
{
    const int bt0 = blockIdx.x * VX_BT;
    const int r = blockIdx.y;
    const int g = blockIdx.z;                 // gate 0..3
    const int j = threadIdx.x & 127;
    const int c = g * 128 + j;
    const int half_ = threadIdx.x >> 7;
    __shared__ float vv_s[VX_BT][DV];

    for (int i = threadIdx.x; i < VX_BT * DV; i += 256)
        vv_s[i >> 7][i & 127] = vG[(size_t)(bt0 + (i >> 7)) * DV + (i & 127)];
    __syncthreads();

    float acc[16];
    #pragma unroll
    for (int i = 0; i < 16; ++i) acc[i] = 0.0f;

    const float* wp = Wx_rnn + ((size_t)r * DV) * 512 + c;
    const int btb = half_ * 16;
    #pragma unroll 4
    for (int d = 0; d < DV; ++d) {
        float w = wp[(size_t)d * 512];
        #pragma unroll
        for (int i = 0; i < 16; ++i) acc[i] += vv_s[btb + i][d] * w;
    }
    #pragma unroll
    for (int i = 0; i < 16; ++i) {
        size_t idx = (((size_t)(bt0 + btb + i) * Rdim + r) * 128 + j) * 4 + g;
        if (m16) VX16[idx] = __float2half(acc[i]);
        else     VX32[idx] = acc[i];
    }
}

// ---------------- Kernel 1d (REWRITTEN): WK[bt,r,h] = Wq_in[r,h,:] · k[bt,:] ----------------
// LDS-tiled: 64 bt x 128 h per block, one r. Summation order kept bit-identical
// to the original (per-d4 grouping w0*k0 + w1*k1 + w2*k2 + w3*k3, d4 = 0..15).
#define WK_BT 64
__global__ __launch_bounds__(256) void k_wk(
    const float* __restrict__ kG, const float* __restrict__ Wq_in,
    float* __restrict__ WK)
{
    const int bt0 = blockIdx.x * WK_BT;
    const int r = blockIdx.y;
    const int tid = threadIdx.x;

    __shared__ float wq_s[DK][129];      // [d][h], pad 129: staging + reads conflict-free
    __shared__ float ks_s[WK_BT][68];    // [bt][d], 272B rows (16B-aligned float4 reads)

    // stage Wq_in[r] transposed: coalesced global reads, bank-spread LDS writes
    for (int e = tid; e < Hdim * DK; e += 256) {
        int d = e & 63, h = e >> 6;
        wq_s[d][h] = Wq_in[((size_t)r * Hdim + h) * DK + d];
    }
    // stage k-tile: coalesced
    for (int e = tid; e < WK_BT * DK; e += 256) {
        int bt = e >> 6, d = e & 63;
        ks_s[bt][d] = kG[(size_t)(bt0 + bt) * DK + d];
    }
    __syncthreads();

    const int h = tid & 127;
    const int btb = (tid >> 7) * 32;

    float acc[32];
    #pragma unroll
    for (int i = 0; i < 32; ++i) acc[i] = 0.0f;

    #pragma unroll 4
    for (int d4 = 0; d4 < 16; ++d4) {
        float w0 = wq_s[4 * d4 + 0][h];
        float w1 = wq_s[4 * d4 + 1][h];
        float w2 = wq_s[4 * d4 + 2][h];
        float w3 = wq_s[4 * d4 + 3][h];
        #pragma unroll
        for (int b32 = 0; b32 < 32; ++b32) {
            float4 k4 = *(const float4*)&ks_s[btb + b32][d4 * 4];
            acc[b32] += w0 * k4.x + w1 * k4.y + w2 * k4.z + w3 * k4.w;
        }
    }

    #pragma unroll
    for (int b32 = 0; b32 < 32; ++b32)
        WK[((size_t)(bt0 + btb + b32) * Rdim + r) * Hdim + h] = acc[b32];
}

// ---------------- Kernel 1e: fp16-pack hot weights, {4 K x 4 cols} per 32B group ----------------
// Wh_p [r][d4<32][c4<128][16] <- Wh_rnn[r][128][512]
// Wc_p [r][d4<32][e4<96][16]  <- [Wq_c|Wk_c|Wv_c][r][128][128] (cols 0..383)
// Wo_p [r][d4<32][c4<32][16]  <- Wout_c[r][128][128]
// group idx j<16: d = 4*d4 + (j>>2), col = 4*c4 + (j&3)
#define NH_P (Rdim * 32 * 128 * 16)
#define NC_P (Rdim * 32 * 96 * 16)
#define NO_P (Rdim * 32 * 32 * 16)
__global__ __launch_bounds__(256) void k_pack(
    const float* __restrict__ Wh_rnn,
    const float* __restrict__ Wq_c, const float* __restrict__ Wk_c,
    const float* __restrict__ Wv_c, const float* __restrict__ Wout_c,
    __half* __restrict__ Wh_p, __half* __restrict__ Wc_p, __half* __restrict__ Wo_p)
{
    int i = blockIdx.x * 256 + threadIdx.x;
    if (i < NH_P) {
        int j = i & 15, t1 = i >> 4;
        int c4 = t1 & 127, t2 = t1 >> 7;
        int d4 = t2 & 31, r = t2 >> 5;
        int d = 4 * d4 + (j >> 2), col = 4 * c4 + (j & 3);
        Wh_p[i] = __float2half(Wh_rnn[((size_t)r * Hdim + d) * 512 + col]);
    } else if (i < NH_P + NC_P) {
        int ii = i - NH_P;
        int j = ii & 15, t1 = ii >> 4;
        int e4 = t1 % 96, t2 = t1 / 96;
        int d4 = t2 & 31, r = t2 >> 5;
        int d = 4 * d4 + (j >> 2), col = 4 * e4 + (j & 3);
        int mId = col >> 7, colm = col & 127;
        const float* src = (mId == 0 ? Wq_c : (mId == 1 ? Wk_c : Wv_c));
        Wc_p[ii] = __float2half(src[((size_t)r * Hdim + d) * Hdim + colm]);
    } else if (i < NH_P + NC_P + NO_P) {
        int ii = i - NH_P - NC_P;
        int j = ii & 15, t1 = ii >> 4;
        int c4 = t1 & 31, t2 = t1 >> 5;
        int d4 = t2 & 31, r = t2 >> 5;
        int d = 4 * d4 + (j >> 2), col = 4 * c4 + (j & 3);
        Wo_p[ii] = __float2half(Wout_c[((size_t)r * Hdim + d) * Hdim + col]);
    }
}

// 16 MACs: 4 K-values (hq) x 4 cols, weights as 16 halves (two 16B loads)
__device__ __forceinline__ void fma16(float4& acc, const __half* w, const float4 hq) {
    float4 wa = *(const float4*)(w);
    float4 wb = *(const float4*)(w + 8);
    const __half2* ha = (const __half2*)&wa;
    const __half2* hb = (const __half2*)&wb;
    float2 c;
    c = __half22float2(ha[0]); acc.x += hq.x * c.x; acc.y += hq.x * c.y;
    c = __half22float2(ha[1]); acc.z += hq.x * c.x; acc.w += hq.x * c.y;
    c = __half22float2(ha[2]); acc.x += hq.y * c.x; acc.y += hq.y * c.y;
    c = __half22float2(ha[3]); acc.z += hq.y * c.x; acc.w += hq.y * c.y;
    c = __half22float2(hb[0]); acc.x += hq.z * c.x; acc.y += hq.z * c.y;
    c = __half22float2(hb[1]); acc.z += hq.z * c.x; acc.w += hq.z * c.y;
    c = __half22float2(hb[2]); acc.x += hq.w * c.x; acc.y += hq.w * c.y;
    c = __half22float2(hb[3]); acc.z += hq.w * c.x; acc.w += hq.w * c.y;
}

// ---------------- Kernel 2: sequential scan, one block per batch, 5 barriers/step ----------------
__global__ __launch_bounds__(768) void k_seq(
    const float* __restrict__ statics,
    const float* __restrict__ h0, const float* __restrict__ c0,
    const __half* __restrict__ Wh_p, const __half* __restrict__ Wc_p,
    const __half* __restrict__ Wo_p,
    const float* __restrict__ b_rnn,
    const float* __restrict__ W1, const float* __restrict__ b1,
    const float* __restrict__ W2, const float* __restrict__ b2,
    const float* __restrict__ ghG, const float* __restrict__ WK,
    const float* __restrict__ WB,
    const float* __restrict__ VX32, const __half* __restrict__ VX16, const int m16,
    const float* __restrict__ BX,
    float* __restrict__ out)
{
    const int b = blockIdx.x;
    const int tid = threadIdx.x;
    const int wave = tid >> 6, lane = tid & 63;
    const int r_ = tid >> 7, j_ = tid & 127;

    __shared__ float hs[Rdim][Hdim], cs[Rdim][Hdim], hn[Rdim][Hdim], cn[Rdim][Hdim];
    __shared__ float pre_s[Rdim][4 * Hdim];
    __shared__ float qc[Rdim][Hdim], kc[Rdim][Hdim], vc[Rdim][Hdim], ctx[Rdim][Hdim];
    __shared__ float BX_s[Rdim][512], brnn_s[Rdim][512];
    __shared__ float WB_s[Rdim][Hdim];
    __shared__ float s0s[8], p0s[8], p1s[8], mk[8];

    // preload per-model constants into LDS (once)
    ((float4*)&BX_s[0][0])[tid]   = ((const float4*)BX)[tid];
    ((float4*)&brnn_s[0][0])[tid] = ((const float4*)b_rnn)[tid];
    (&WB_s[0][0])[tid] = WB[tid];

    // per-step data prefetch for t=0
    int bt = b * Tdim;
    float ghr = ghG[(size_t)bt * Hdim + j_];
    float4 vx4;
    if (m16) {
        const __half2* vp = (const __half2*)(VX16 + (((size_t)bt * Rdim + r_) * 128 + j_) * 4);
        float2 a = __half22float2(vp[0]), bb = __half22float2(vp[1]);
        vx4 = make_float4(a.x, a.y, bb.x, bb.y);
    } else {
        vx4 = *(const float4*)(VX32 + (((size_t)bt * Rdim + r_) * 128 + j_) * 4);
    }
    float wk0 = 0.0f, wk1 = 0.0f;
    if (wave < Rdim) {
        wk0 = WK[((size_t)bt * Rdim + wave) * Hdim + lane];
        wk1 = WK[((size_t)bt * Rdim + wave) * Hdim + lane + 64];
    }

    // init carry with decay(t=0) folded in
    hs[r_][j_] = h0[(size_t)b * 768 + tid] * ghr;
    cs[r_][j_] = c0[(size_t)b * 768 + tid];
    __syncthreads();

    for (int t = 0; t < Tdim; ++t) {
        bt = b * Tdim + t;
        const bool lastt = (t == Tdim - 1);

        // ==== phase 1: B scores (waves 0-5) in parallel with E = hs @ Wh (all waves)
        if (wave < Rdim) {
            float hv0 = hs[wave][lane], hv1 = hs[wave][lane + 64];
            float a0 = hv0 * wk0 + hv1 * wk1;
            float a1 = hv0 * WB_s[wave][lane] + hv1 * WB_s[wave][lane + 64];
            #pragma unroll
            for (int off = 32; off > 0; off >>= 1) {
                a0 += __shfl_xor(a0, off);
                a1 += __shfl_xor(a1, off);
            }
            if (lane == 0) {
                float sv0 = a0 * 0.125f, sv1 = a1 * 0.125f;
                s0s[wave] = sv0;
                float m = fmaxf(sv0, sv1);
                float e0 = expf(sv0 - m), e1 = expf(sv1 - m);
                float inv = 1.0f / (e0 + e1);
                p0s[wave] = e0 * inv; p1s[wave] = e1 * inv;
            }
        }
        {
            float4 acc = make_float4(0.f, 0.f, 0.f, 0.f);
            const __half* wp = Wh_p + (((size_t)r_ * 32) * 128 + j_) * 16;
            #pragma unroll 8
            for (int d4 = 0; d4 < 32; ++d4) {
                float4 hq = *(const float4*)&hs[r_][d4 * 4];
                fma16(acc, wp, hq);
                wp += 128 * 16;
            }
            *(float4*)&pre_s[r_][j_ * 4] = acc;
        }
        __syncthreads();

        // ==== phase 2: top-k mask (6 thr) + LSTM with fused bias/VX/BX (all)
        if (tid < Rdim) {
            int rank = 0;
            #pragma unroll
            for (int j = 0; j < Rdim; ++j)
                rank += (s0s[j] > s0s[tid] || (s0s[j] == s0s[tid] && j < tid)) ? 1 : 0;
            mk[tid] = (rank < KACT) ? 1.0f : 0.0f;
        }
        {
            float P0v = p0s[r_], P1v = p1s[r_];
            float ig = pre_s[r_][j_]       + P0v * vx4.x + P1v * BX_s[r_][j_]       + brnn_s[r_][j_];
            float fg = pre_s[r_][128 + j_] + P0v * vx4.y + P1v * BX_s[r_][128 + j_] + brnn_s[r_][128 + j_];
            float gg = pre_s[r_][256 + j_] + P0v * vx4.z + P1v * BX_s[r_][256 + j_] + brnn_s[r_][256 + j_];
            float og = pre_s[r_][384 + j_] + P0v * vx4.w + P1v * BX_s[r_][384 + j_] + brnn_s[r_][384 + j_];
            float cnew = sigmoidf_(fg) * cs[r_][j_] + sigmoidf_(ig) * tanhf(gg);
            float hnew = sigmoidf_(og) * tanhf(cnew);
            cn[r_][j_] = cnew;
            hn[r_][j_] = hnew;
        }
        __syncthreads();

        // ==== phase 3: register-prefetch t+1 (all) + G qkv matvec (576 thr)
        if (!lastt) {
            const int bt1 = bt + 1;
            ghr = ghG[(size_t)bt1 * Hdim + j_];
            if (m16) {
                const __half2* vp = (const __half2*)(VX16 + (((size_t)bt1 * Rdim + r_) * 128 + j_) * 4);
                float2 a = __half22float2(vp[0]), bb = __half22float2(vp[1]);
                vx4 = make_float4(a.x, a.y, bb.x, bb.y);
            } else {
                vx4 = *(const float4*)(VX32 + (((size_t)bt1 * Rdim + r_) * 128 + j_) * 4);
            }
            if (wave < Rdim) {
                wk0 = WK[((size_t)bt1 * Rdim + wave) * Hdim + lane];
                wk1 = WK[((size_t)bt1 * Rdim + wave) * Hdim + lane + 64];
            }
        } else {
            ghr = 1.0f;
        }
        if (tid < 576) {
            const int rG = tid / 96, e4 = tid % 96;
            float4 acc = make_float4(0.f, 0.f, 0.f, 0.f);
            const __half* wp = Wc_p + (((size_t)rG * 32) * 96 + e4) * 16;
            #pragma unroll 8
            for (int d4 = 0; d4 < 32; ++d4) {
                float4 hq = *(const float4*)&hn[rG][d4 * 4];
                fma16(acc, wp, hq);
                wp += 96 * 16;
            }
            int col = e4 * 4, mId = col >> 7, colm = col & 127;
            float* dst = (mId == 0 ? &qc[rG][colm] : (mId == 1 ? &kc[rG][colm] : &vc[rG][colm]));
            *(float4*)dst = acc;
        }
        __syncthreads();

        // ==== phase 4: fused attention scores + softmax + ctx (96 thr, all in regs)
        if (tid < 96) {
            int rr = tid >> 4, h = (tid >> 2) & 3, q = tid & 3;
            float4 Q[8];
            #pragma unroll
            for (int i = 0; i < 8; ++i) Q[i] = *(const float4*)&qc[rr][h * 32 + 4 * i];
            float sc[Rdim];
            #pragma unroll
            for (int ss = 0; ss < Rdim; ++ss) {
                float acc = 0.0f;
                #pragma unroll
                for (int i = 0; i < 8; ++i) {
                    float4 kq = *(const float4*)&kc[ss][h * 32 + 4 * i];
                    acc += Q[i].x * kq.x + Q[i].y * kq.y + Q[i].z * kq.z + Q[i].w * kq.w;
                }
                sc[ss] = acc * 0.17677669529663687f;
            }
            float m = sc[0];
            #pragma unroll
            for (int ss = 1; ss < Rdim; ++ss) m = fmaxf(m, sc[ss]);
            float e[Rdim], sum = 0.0f;
            #pragma unroll
            for (int ss = 0; ss < Rdim; ++ss) { e[ss] = expf(sc[ss] - m); sum += e[ss]; }
            float w = mk[rr] / sum;
            float4 a0 = make_float4(0.f, 0.f, 0.f, 0.f), a1 = a0;
            #pragma unroll
            for (int ss = 0; ss < Rdim; ++ss) {
                float cl = e[ss] * w;
                float4 v0 = *(const float4*)&vc[ss][h * 32 + q * 8];
                float4 v1 = *(const float4*)&vc[ss][h * 32 + q * 8 + 4];
                a0.x += cl * v0.x; a0.y += cl * v0.y; a0.z += cl * v0.z; a0.w += cl * v0.w;
                a1.x += cl * v1.x; a1.y += cl * v1.y; a1.z += cl * v1.z; a1.w += cl * v1.w;
            }
            *(float4*)&ctx[rr][h * 32 + q * 8] = a0;
            *(float4*)&ctx[rr][h * 32 + q * 8 + 4] = a1;
        }
        __syncthreads();

        // ==== phase 5: Wout matvec + state update + decay(t+1) folded in
        if (tid < 192) {
            const int rK = tid / 32, c4 = tid % 32;
            if (mk[rK] > 0.5f) {
                float4 acc = make_float4(0.f, 0.f, 0.f, 0.f);
                const __half* wp = Wo_p + (((size_t)rK * 32) * 32 + c4) * 16;
                #pragma unroll 8
                for (int d4 = 0; d4 < 32; ++d4) {
                    float4 cq = *(const float4*)&ctx[rK][d4 * 4];
                    fma16(acc, wp, cq);
                    wp += 32 * 16;
                }
                float4 hq = *(const float4*)&hn[rK][c4 * 4];
                float4 g4 = make_float4(1.f, 1.f, 1.f, 1.f);
                if (!lastt) g4 = *(const float4*)&ghG[(size_t)(bt + 1) * Hdim + c4 * 4];
                float4 o;
                o.x = (acc.x + hq.x) * g4.x;
                o.y = (acc.y + hq.y) * g4.y;
                o.z = (acc.z + hq.z) * g4.z;
                o.w = (acc.w + hq.w) * g4.w;
                *(float4*)&hs[rK][c4 * 4] = o;
            }
        }
        {
            if (mk[r_] > 0.5f) cs[r_][j_] = cn[r_][j_];
            else               hs[r_][j_] *= ghr;   // inactive row: keep decayed h_old
        }
        __syncthreads();
    }

    // Head: out[b] = (concat(hs, statics) @ W1 + b1) @ W2 + b2
    if (tid < 64) {
        float a = b1[tid];
        const float* hsf = &hs[0][0];
        #pragma unroll 4
        for (int i = 0; i < Rdim * Hdim; ++i) a += hsf[i] * W1[i * 64 + tid];
        #pragma unroll
        for (int i = 0; i < Sdim; ++i) a += statics[b * Sdim + i] * W1[(Rdim * Hdim + i) * 64 + tid];
        float pv = a * W2[tid];
        #pragma unroll
        for (int off = 32; off > 0; off >>= 1) pv += __shfl_xor(pv, off);
        if (tid == 0) out[b] = pv + b2[0];
    }
}

extern "C" void kernel_launch(void* const* d_in, const int* in_sizes, int n_in,
                              void* d_out, int out_size, void* d_ws, size_t ws_size,
                              hipStream_t stream) {
    const float* x       = (const float*)d_in[0];
    const float* statics = (const float*)d_in[1];
    const float* mask    = (const float*)d_in[2];
    const float* delta   = (const float*)d_in[3];
    const float* xlast   = (const float*)d_in[4];
    const float* xmean   = (const float*)d_in[5];
    const float* h0      = (const float*)d_in[6];
    const float* c0      = (const float*)d_in[7];
    const float* Wgx     = (const float*)d_in[8];
    const float* bgx     = (const float*)d_in[9];
    const float* Wgh     = (const float*)d_in[10];
    const float* bgh     = (const float*)d_in[11];
    const float* Wk_in   = (const float*)d_in[12];
    const float* bk_in   = (const float*)d_in[13];
    const float* Wv_in   = (const float*)d_in[14];
    const float* bv_in   = (const float*)d_in[15];
    const float* Wq_in   = (const float*)d_in[16];
    const float* Wx_rnn  = (const float*)d_in[17];
    const float* Wh_rnn  = (const float*)d_in[18];
    const float* b_rnn   = (const float*)d_in[19];
    const float* Wq_c    = (const float*)d_in[20];
    const float* Wk_c    = (const float*)d_in[21];
    const float* Wv_c    = (const float*)d_in[22];
    const float* Wout_c  = (const float*)d_in[23];
    const float* W1      = (const float*)d_in[24];
    const float* b1      = (const float*)d_in[25];
    const float* W2      = (const float*)d_in[26];
    const float* b2      = (const float*)d_in[27];

    const size_t nGh  = (size_t)Bdim * Tdim * Hdim;
    const size_t nK   = (size_t)Bdim * Tdim * DK;
    const size_t nV   = (size_t)Bdim * Tdim * DV;
    const size_t nBX  = (size_t)Rdim * 512;
    const size_t nWB  = (size_t)Rdim * Hdim;
    const size_t nWK  = (size_t)Bdim * Tdim * Rdim * Hdim;
    const size_t nPck = (size_t)(NH_P + NC_P + NO_P) / 2;
    const size_t nVX  = (size_t)Bdim * Tdim * Rdim * 512;

    float*  ws   = (float*)d_ws;
    float*  ghG  = ws;
    float*  kG   = ghG + nGh;
    float*  vG   = kG + nK;
    float*  BX   = vG + nV;
    float*  WB   = BX + nBX;
    float*  WK   = WB + nWB;
    __half* Wh_p = (__half*)(WK + nWK);
    __half* Wc_p = Wh_p + NH_P;
    __half* Wo_p = Wc_p + NC_P;
    float*  VXf  = WK + nWK + nPck;
    __half* VXh  = (__half*)VXf;

    const size_t base = nGh + nK + nV + nBX + nWB + nWK + nPck;
    const int m16 = (ws_size >= (base + nVX) * sizeof(float)) ? 0 : 1;

    k_pre<<<dim3(Bdim * Tdim), dim3(128), 0, stream>>>(
        x, mask, delta, xlast, xmean, Wgx, bgx, Wgh, bgh,
        Wk_in, bk_in, Wv_in, bv_in, ghG, kG, vG);

    k_bx<<<dim3((Rdim * 512 + Rdim * Hdim + 255) / 256), dim3(256), 0, stream>>>(
        bv_in, Wx_rnn, bk_in, Wq_in, BX, WB);

    k_wk<<<dim3(Bdim * Tdim / WK_BT, Rdim), dim3(256), 0, stream>>>(kG, Wq_in, WK);

    k_pack<<<dim3((NH_P + NC_P + NO_P + 255) / 256), dim3(256), 0, stream>>>(
        Wh_rnn, Wq_c, Wk_c, Wv_c, Wout_c, Wh_p, Wc_p, Wo_p);

    k_vx<<<dim3(Bdim * Tdim / VX_BT, Rdim, 4), dim3(256), 0, stream>>>(
        vG, Wx_rnn, VXf, VXh, m16);

    k_seq<<<dim3(Bdim), dim3(768), 0, stream>>>(
        statics, h0, c0, Wh_p, Wc_p, Wo_p, b_rnn,
        W1, b1, W2, b2, ghG, WK, WB, VXf, VXh, m16, BX, (float*)d_out);
}